// Round 10
// baseline (241.163 us; speedup 1.0000x reference)
//
#include <hip/hip_runtime.h>
#include <stdint.h>

typedef unsigned short u16;
typedef short bf16x8 __attribute__((ext_vector_type(8)));
typedef float f32x4 __attribute__((ext_vector_type(4)));
typedef float f32x16 __attribute__((ext_vector_type(16)));

#define MB (1024L*1024L)

__device__ inline u16 f2bf(float f) {
  union { float f; unsigned u; } v; v.f = f;
  unsigned r = (v.u + 0x7FFFu + ((v.u >> 16) & 1u)) >> 16;
  return (u16)r;
}

__device__ inline float bf2f(u16 u) {
  union { unsigned u; float f; } v; v.u = ((unsigned)u) << 16; return v.f;
}

__device__ inline unsigned cvtpk(float lo, float hi) {
  unsigned r;
  asm("v_cvt_pk_bf16_f32 %0, %1, %2" : "=v"(r) : "v"(lo), "v"(hi));
  return r;
}

#define GLOAD16(gptr, lptr) \
  __builtin_amdgcn_global_load_lds((__attribute__((address_space(1))) void*)(gptr), \
                                   (__attribute__((address_space(3))) void*)(lptr), 16, 0, 0)

// ---------------- merged weight prep: 6 transposes + bias concat, ONE launch ----------------
__global__ __launch_bounds__(256) void wprep(
    const float* __restrict__ Wq, const float* __restrict__ Wk,
    const float* __restrict__ Wv, const float* __restrict__ Wo,
    const float* __restrict__ W1, const float* __restrict__ W2,
    const float* __restrict__ bq, const float* __restrict__ bk,
    const float* __restrict__ bv,
    u16* __restrict__ WqkvT, u16* __restrict__ WoT,
    u16* __restrict__ W1T, u16* __restrict__ W2T, float* __restrict__ bqkv) {
  const int blk = blockIdx.x;
  const int tid = threadIdx.x;
  if (blk >= 12288) {  // bias concat (4 blocks x 256 = 1024)
    int i = (blk - 12288) * 256 + tid;
    bqkv[i] = bq[i]; bqkv[1024 + i] = bk[i]; bqkv[2048 + i] = bv[i];
    return;
  }
  const float* W; u16* WT; int K, N, tb;
  if (blk < 4096) {
    K = 1024; N = 1024;
    if (blk < 1024)      { W = Wq; WT = WqkvT;               tb = blk; }
    else if (blk < 2048) { W = Wk; WT = WqkvT + 1024 * 1024; tb = blk - 1024; }
    else if (blk < 3072) { W = Wv; WT = WqkvT + 2048 * 1024; tb = blk - 2048; }
    else                 { W = Wo; WT = WoT;                 tb = blk - 3072; }
  } else if (blk < 8192) { W = W1; WT = W1T; K = 1024; N = 4096; tb = blk - 4096; }
  else                   { W = W2; WT = W2T; K = 4096; N = 1024; tb = blk - 8192; }

  __shared__ float tile[32][33];
  const int nbn = N >> 5;
  const int bk_ = tb / nbn;
  const int bn = tb % nbn;
  const int r = tid >> 3;
  const int c4 = (tid & 7) << 2;
  const float4 v = *(const float4*)(W + (size_t)(bk_ * 32 + r) * N + bn * 32 + c4);
  tile[r][c4 + 0] = v.x; tile[r][c4 + 1] = v.y;
  tile[r][c4 + 2] = v.z; tile[r][c4 + 3] = v.w;
  __syncthreads();
  ushort4 o;
  o.x = f2bf(tile[c4 + 0][r]); o.y = f2bf(tile[c4 + 1][r]);
  o.z = f2bf(tile[c4 + 2][r]); o.w = f2bf(tile[c4 + 3][r]);
  *(ushort4*)(WT + (size_t)(bn * 32 + r) * K + bk_ * 32 + c4) = o;
}

// ---------------- LayerNorm fp32 -> bf16, D=1024, one block per row ----------------
__global__ __launch_bounds__(256) void ln_kernel(const float* __restrict__ x,
                                                 const float* __restrict__ gamma,
                                                 const float* __restrict__ beta,
                                                 u16* __restrict__ out) {
  const int row = blockIdx.x;
  const int tid = threadIdx.x;
  const float4 v = *(const float4*)(x + (size_t)row * 1024 + tid * 4);
  float s = v.x + v.y + v.z + v.w;
  float s2 = v.x * v.x + v.y * v.y + v.z * v.z + v.w * v.w;
#pragma unroll
  for (int m = 1; m < 64; m <<= 1) {
    s += __shfl_xor(s, m, 64);
    s2 += __shfl_xor(s2, m, 64);
  }
  __shared__ float red[8];
  const int w = tid >> 6;
  if ((tid & 63) == 0) { red[w] = s; red[4 + w] = s2; }
  __syncthreads();
  s = red[0] + red[1] + red[2] + red[3];
  s2 = red[4] + red[5] + red[6] + red[7];
  const float mean = s * (1.0f / 1024.0f);
  const float var = s2 * (1.0f / 1024.0f) - mean * mean;
  const float rstd = rsqrtf(var + 1e-5f);
  const float4 g = *(const float4*)(gamma + tid * 4);
  const float4 b = *(const float4*)(beta + tid * 4);
  ushort4 o;
  o.x = f2bf(g.x * (v.x - mean) * rstd + b.x);
  o.y = f2bf(g.y * (v.y - mean) * rstd + b.y);
  o.z = f2bf(g.z * (v.z - mean) * rstd + b.z);
  o.w = f2bf(g.w * (v.w - mean) * rstd + b.w);
  *(ushort4*)(out + (size_t)row * 1024 + tid * 4) = o;
}

// ---------------- GEMM 256x128, 8 waves, triple-buffered, 4 fine phases/K-tile ----------------
// C[M,N] = A[M,K] @ BT[N,K]^T. BK=64. counted vmcnt(6). Grid = 16*nBN, XCD-swizzled.
// EPI 0: bf16 = acc+bias ; 2: bf16 = gelu(acc+bias).
template <int EPI>
__global__ __launch_bounds__(512, 1)
void gemm256(const u16* __restrict__ A, const u16* __restrict__ BT,
             const float* __restrict__ bias, void* __restrict__ outp,
             int M, int N, int K) {
  __shared__ __align__(16) u16 As[3][256 * 64];  // 96KB
  __shared__ __align__(16) u16 Bs[3][128 * 64];  // 48KB
  const int nBN = N >> 7;
  const int blk = blockIdx.x;
  const int xcd = blk & 7;
  const int rr = blk >> 3;
  const int bm = xcd * 2 + rr / nBN;
  const int bn = rr % nBN;
  const int tid = threadIdx.x;
  const int lane = tid & 63;
  const int wid = tid >> 6;
  const int wm = wid >> 2;   // 0..1 : 128 rows
  const int wn = wid & 3;    // 0..3 : 32 cols
  const int e4 = lane >> 4;
  const int sx = lane & 7;   // swizzle key (row&7 for both A and B frag rows)

  const int abase0 = (wm * 128 + (lane & 15)) * 64;
  const int bbase0 = (wn * 32 + (lane & 15)) * 64;
  const int chs0 = ((e4 ^ sx) & 7) << 3;            // kk=0 chunk offset (elems)
  const int chs1 = (((4 + e4) ^ sx) & 7) << 3;      // kk=1

  // staging addresses: LDS linear dest, pre-swizzled global source
  size_t ga[4]; int loa[4];
#pragma unroll
  for (int c = 0; c < 4; ++c) {
    int idx = tid + (c << 9);
    int row = idx >> 3;
    int ch = (idx & 7) ^ (row & 7);
    ga[c] = (size_t)(bm * 256 + row) * K + (ch << 3);
    loa[c] = idx << 4;
  }
  size_t gb[2]; int lob[2];
#pragma unroll
  for (int c = 0; c < 2; ++c) {
    int idx = tid + (c << 9);
    int row = idx >> 3;
    int ch = (idx & 7) ^ (row & 7);
    gb[c] = (size_t)(bn * 128 + row) * K + (ch << 3);
    lob[c] = idx << 4;
  }

  f32x4 acc[8][2] = {};
  const int nt = K >> 6;

#define STG_A(tt, dst, c) GLOAD16(A + ga[c] + (size_t)(tt) * 64, (char*)(dst) + loa[c])
#define STG_B(tt, dst, c) GLOAD16(BT + gb[c] + (size_t)(tt) * 64, (char*)(dst) + lob[c])
#define LDA(p, m, ch) (*(const bf16x8*)((p) + abase0 + (m) * 1024 + (ch)))
#define LDB(p, n, ch) (*(const bf16x8*)((p) + bbase0 + (n) * 1024 + (ch)))
#define MFMA8(mh, b0, b1) do { \
  _Pragma("unroll") for (int mm = 0; mm < 4; ++mm) { \
    acc[(mh)*4+mm][0] = __builtin_amdgcn_mfma_f32_16x16x32_bf16(a[mm], b0, acc[(mh)*4+mm][0], 0, 0, 0); \
    acc[(mh)*4+mm][1] = __builtin_amdgcn_mfma_f32_16x16x32_bf16(a[mm], b1, acc[(mh)*4+mm][1], 0, 0, 0); \
  } \
} while (0)

  // prologue: stage tiles 0 (buf0) and 1 (buf1)
#pragma unroll
  for (int c = 0; c < 4; ++c) STG_A(0, As[0], c);
#pragma unroll
  for (int c = 0; c < 2; ++c) STG_B(0, Bs[0], c);
#pragma unroll
  for (int c = 0; c < 4; ++c) STG_A(1, As[1], c);
#pragma unroll
  for (int c = 0; c < 2; ++c) STG_B(1, Bs[1], c);

  u16 *Acur = As[0], *Anxt = As[1], *Astg = As[2];
  u16 *Bcur = Bs[0], *Bnxt = Bs[1], *Bstg = Bs[2];

  for (int t = 0; t < nt; ++t) {
    if (t + 1 < nt) asm volatile("s_waitcnt vmcnt(6)" ::: "memory");
    else            asm volatile("s_waitcnt vmcnt(0)" ::: "memory");
    __builtin_amdgcn_s_barrier();   // tile t published for ALL waves
    const bool st = (t + 2 < nt);
    bf16x8 a[4], b0, b1;

    // phase 0: kk=0, mh=0
    a[0] = LDA(Acur, 0, chs0); a[1] = LDA(Acur, 1, chs0);
    a[2] = LDA(Acur, 2, chs0); a[3] = LDA(Acur, 3, chs0);
    b0 = LDB(Bcur, 0, chs0);   b1 = LDB(Bcur, 1, chs0);
    if (st) { STG_A(t + 2, Astg, 0); STG_A(t + 2, Astg, 1); }
    __builtin_amdgcn_s_barrier();
    __builtin_amdgcn_s_setprio(1);
    MFMA8(0, b0, b1);
    __builtin_amdgcn_s_setprio(0);
    __builtin_amdgcn_s_barrier();

    // phase 1: kk=0, mh=1
    a[0] = LDA(Acur, 4, chs0); a[1] = LDA(Acur, 5, chs0);
    a[2] = LDA(Acur, 6, chs0); a[3] = LDA(Acur, 7, chs0);
    if (st) { STG_A(t + 2, Astg, 2); STG_A(t + 2, Astg, 3); }
    __builtin_amdgcn_s_barrier();
    __builtin_amdgcn_s_setprio(1);
    MFMA8(1, b0, b1);
    __builtin_amdgcn_s_setprio(0);
    __builtin_amdgcn_s_barrier();

    // phase 2: kk=1, mh=0
    a[0] = LDA(Acur, 0, chs1); a[1] = LDA(Acur, 1, chs1);
    a[2] = LDA(Acur, 2, chs1); a[3] = LDA(Acur, 3, chs1);
    b0 = LDB(Bcur, 0, chs1);   b1 = LDB(Bcur, 1, chs1);
    if (st) { STG_B(t + 2, Bstg, 0); }
    __builtin_amdgcn_s_barrier();
    __builtin_amdgcn_s_setprio(1);
    MFMA8(0, b0, b1);
    __builtin_amdgcn_s_setprio(0);
    __builtin_amdgcn_s_barrier();

    // phase 3: kk=1, mh=1
    a[0] = LDA(Acur, 4, chs1); a[1] = LDA(Acur, 5, chs1);
    a[2] = LDA(Acur, 6, chs1); a[3] = LDA(Acur, 7, chs1);
    if (st) { STG_B(t + 2, Bstg, 1); }
    __builtin_amdgcn_s_barrier();
    __builtin_amdgcn_s_setprio(1);
    MFMA8(1, b0, b1);
    __builtin_amdgcn_s_setprio(0);
    __builtin_amdgcn_s_barrier();

    // rotate buffers: (cur, nxt, stg) <- (nxt, stg, cur)
    u16* ta = Acur; Acur = Anxt; Anxt = Astg; Astg = ta;
    u16* tb = Bcur; Bcur = Bnxt; Bnxt = Bstg; Bstg = tb;
  }
#undef STG_A
#undef STG_B
#undef LDA
#undef LDB
#undef MFMA8

  const int rbase = bm * 256 + wm * 128;
  const int cbase = bn * 128 + wn * 32;
#pragma unroll
  for (int n = 0; n < 2; ++n) {
    const int col = cbase + n * 16 + (lane & 15);
    const float bv = bias[col];
#pragma unroll
    for (int m = 0; m < 8; ++m) {
      const int row0 = rbase + m * 16 + e4 * 4;
#pragma unroll
      for (int r = 0; r < 4; ++r) {
        const int row = row0 + r;
        float v = acc[m][n][r] + bv;
        if (EPI == 2) {
          float tt = v * (1.0f + 0.044715f * v * v);
          float sg = 1.0f / (1.0f + __expf(-1.5957691216057308f * tt));
          ((u16*)outp)[(size_t)row * N + col] = f2bf(v * sg);
        } else {
          ((u16*)outp)[(size_t)row * N + col] = f2bf(v);
        }
      }
    }
  }
}

// ---------------- GEMM: C[M,N] = A[M,K](bf16) @ BT[N,K](bf16)^T (128-row tile) ----------------
// BK=64, dbuf, depth-2 prefetch, counted vmcnt, raw barriers, setprio; XCD-swizzled grid.
// Used for O-proj and MLP2 (N=1024). EPI 1: f32 = acc + bias + res.
template <int EPI, int BN>
__global__ __launch_bounds__(256, (BN == 64) ? 3 : 2)
void gemm_bt(const u16* __restrict__ A, const u16* __restrict__ BT,
             const float* __restrict__ bias, const float* __restrict__ res,
             void* __restrict__ outp, int M, int N, int K) {
  constexpr int MF = (BN == 128) ? 4 : 2;
  constexpr int ACH = 4;
  constexpr int BCH = BN / 32;
  constexpr int LOADS = ACH + BCH;
  __shared__ __align__(16) u16 As[2][128 * 64];
  __shared__ __align__(16) u16 Bs[2][BN * 64];
  const int nBN = N / BN;
  const int hw = blockIdx.x;
  const int xcd = hw & 7;
  const int rr = hw >> 3;
  const int bm = xcd * 4 + rr / nBN;
  const int bn = rr % nBN;
  const int tid = threadIdx.x;
  const int lane = tid & 63;
  const int wid = tid >> 6;
  const int wm = (BN == 128) ? (wid >> 1) : wid;
  const int wn = (BN == 128) ? (wid & 1) : 0;
  const int e4 = lane >> 4;

  int abase[MF], ax[MF];
#pragma unroll
  for (int m = 0; m < MF; ++m) {
    int rowa = wm * (MF * 16) + m * 16 + (lane & 15);
    abase[m] = rowa * 64; ax[m] = rowa & 7;
  }
  int bbase[4], bx[4];
#pragma unroll
  for (int n = 0; n < 4; ++n) {
    int rowb = wn * 64 + n * 16 + (lane & 15);
    bbase[n] = rowb * 64; bx[n] = rowb & 7;
  }

  size_t ga[ACH]; int loa[ACH];
#pragma unroll
  for (int c = 0; c < ACH; ++c) {
    int idx = tid + (c << 8);
    int row = idx >> 3;
    int ch = (idx & 7) ^ (row & 7);
    ga[c] = (size_t)(bm * 128 + row) * K + (ch << 3);
    loa[c] = idx << 4;
  }
  size_t gb[BCH]; int lob[BCH];
#pragma unroll
  for (int c = 0; c < BCH; ++c) {
    int idx = tid + (c << 8);
    int row = idx >> 3;
    int ch = (idx & 7) ^ (row & 7);
    gb[c] = (size_t)(bn * BN + row) * K + (ch << 3);
    lob[c] = idx << 4;
  }

#define STAGE_G(t, bb) do { \
  _Pragma("unroll") for (int c = 0; c < ACH; ++c) \
    GLOAD16(A + ga[c] + (size_t)(t) * 64, (char*)As[bb] + loa[c]); \
  _Pragma("unroll") for (int c = 0; c < BCH; ++c) \
    GLOAD16(BT + gb[c] + (size_t)(t) * 64, (char*)Bs[bb] + lob[c]); \
} while (0)

  f32x4 acc[MF][4] = {};
  const int nt = K >> 6;

  STAGE_G(0, 0);
  STAGE_G(1, 1);

  for (int t = 0; t < nt; ++t) {
    if (t + 1 < nt) {
      asm volatile("s_waitcnt vmcnt(%0)" :: "i"(LOADS) : "memory");
    } else {
      asm volatile("s_waitcnt vmcnt(0)" ::: "memory");
    }
    __builtin_amdgcn_s_barrier();
    const u16* Ap = As[t & 1];
    const u16* Bp = Bs[t & 1];
    bf16x8 af[2][MF], bfr[2][4];
#pragma unroll
    for (int kk = 0; kk < 2; ++kk) {
#pragma unroll
      for (int m = 0; m < MF; ++m)
        af[kk][m] = *(const bf16x8*)(Ap + abase[m] + (((((kk << 2) | e4)) ^ ax[m]) << 3));
#pragma unroll
      for (int n = 0; n < 4; ++n)
        bfr[kk][n] = *(const bf16x8*)(Bp + bbase[n] + (((((kk << 2) | e4)) ^ bx[n]) << 3));
    }
    asm volatile("s_waitcnt lgkmcnt(0)" ::: "memory");
    __builtin_amdgcn_s_barrier();
    if (t + 2 < nt) STAGE_G(t + 2, t & 1);
    __builtin_amdgcn_s_setprio(1);
#pragma unroll
    for (int kk = 0; kk < 2; ++kk)
#pragma unroll
      for (int m = 0; m < MF; ++m)
#pragma unroll
        for (int n = 0; n < 4; ++n)
          acc[m][n] = __builtin_amdgcn_mfma_f32_16x16x32_bf16(af[kk][m], bfr[kk][n], acc[m][n], 0, 0, 0);
    __builtin_amdgcn_s_setprio(0);
  }
#undef STAGE_G

  const int rbase = bm * 128 + wm * (MF * 16);
  const int cbase = bn * BN + wn * 64;
#pragma unroll
  for (int m = 0; m < MF; ++m) {
#pragma unroll
    for (int n = 0; n < 4; ++n) {
      const int col = cbase + n * 16 + (lane & 15);
      const int row0 = rbase + m * 16 + ((lane >> 4) << 2);
      const float bv = bias[col];
#pragma unroll
      for (int r = 0; r < 4; ++r) {
        const int row = row0 + r;
        float v = acc[m][n][r] + bv;
        if (EPI == 1) {
          ((float*)outp)[(size_t)row * N + col] = v + res[(size_t)row * N + col];
        } else if (EPI == 2) {
          float tt = v * (1.0f + 0.044715f * v * v);
          float sg = 1.0f / (1.0f + __expf(-1.5957691216057308f * tt));
          ((u16*)outp)[(size_t)row * N + col] = f2bf(v * sg);
        } else {
          ((u16*)outp)[(size_t)row * N + col] = f2bf(v);
        }
      }
    }
  }
}

// ---------------- causal flash attention, 8-warp 32x32 swapped, software-pipelined ----------------
__global__ __launch_bounds__(512, 2) void attn_kernel(const u16* __restrict__ QKV,
                                                      u16* __restrict__ O) {
  __shared__ __align__(16) u16 SM[5][4096];
  const int T = 2048, LD = 3072;
  const int blk = blockIdx.x;
  const int xcd = blk & 7;
  const int i = blk >> 3;
  const int bh = xcd * 4 + (i & 3);
  const int p = i >> 2;
  const int b = bh >> 4, hd = bh & 15;
  const int tid = threadIdx.x;
  const int lane = tid & 63;
  const int w = tid >> 6;
  const int h = lane >> 5;
  const int cA = p, cB = 15 - p;
  const int myc = (w < 4) ? cA : cB;
  const int qwb = myc * 128 + (w & 3) * 32;
  const int qg = qwb + (lane & 31);
  const int diag = qwb >> 6;
  const int myNt = diag + 1;
  const int nt = 2 * cB + 2;

  const u16* Qb = QKV + (size_t)b * T * LD + hd * 64;
  const u16* Kb = Qb + 1024;
  const u16* Vb = Qb + 2048;

  const float QSC = 0.18033688011112042f;
  bf16x8 qf[4];
#pragma unroll
  for (int s = 0; s < 4; ++s) {
    bf16x8 raw = *(const bf16x8*)(Qb + (size_t)qg * LD + s * 16 + h * 8);
    union { unsigned wd[4]; bf16x8 v; } u;
#pragma unroll
    for (int e = 0; e < 4; ++e)
      u.wd[e] = cvtpk(bf2f((u16)raw[2 * e]) * QSC, bf2f((u16)raw[2 * e + 1]) * QSC);
    qf[s] = u.v;
  }

  f32x16 oacc[2] = {};
  f32x16 sacc[2];
  union PF { unsigned wd[4]; bf16x8 v; } pf[4];
  float m = -INFINITY, l = 0.0f;

  const int srow = tid >> 3;
  const int scol = tid & 7;
  const int kgc = ((scol ^ (srow & 7)) << 3);

#define VWRITE(buf, vvreg) do { \
  _Pragma("unroll") for (int e = 0; e < 8; ++e) { \
    int d = scol * 8 + e; \
    SM[2 + (buf)][(d << 6) | (srow & 7) | ((((srow >> 3) ^ e ^ scol) & 7) << 3)] = (u16)(vvreg)[e]; \
  } \
} while (0)

  GLOAD16(Kb + (size_t)srow * LD + kgc, (char*)SM[0] + tid * 16);
  {
    bf16x8 vv0 = *(const bf16x8*)(Vb + (size_t)srow * LD + scol * 8);
    VWRITE(0, vv0);
  }
  __syncthreads();

  int vPrev = 2, vCur = 0, vNext = 1;
  for (int j = 0; j < nt; ++j) {
    const bool pre = (j + 1 < nt);
    bf16x8 vv;
    if (pre) {
      GLOAD16(Kb + (size_t)((j + 1) * 64 + srow) * LD + kgc, (char*)SM[(j + 1) & 1] + tid * 16);
      vv = *(const bf16x8*)(Vb + (size_t)((j + 1) * 64 + srow) * LD + scol * 8);
    }
    const bool doQK = (j < myNt);
    const bool doPV = (j >= 1) && (j <= myNt);

    __builtin_amdgcn_s_setprio(1);
    if (doQK) {
      const u16* Kp = SM[j & 1];
#pragma unroll
      for (int t = 0; t < 2; ++t) {
#pragma unroll
        for (int r = 0; r < 16; ++r) sacc[t][r] = 0.0f;
#pragma unroll
        for (int s = 0; s < 4; ++s) {
          int row = t * 32 + (lane & 31);
          bf16x8 kf = *(const bf16x8*)(Kp + (row << 6) + ((((2 * s + h) ^ (row & 7)) & 7) << 3));
          sacc[t] = __builtin_amdgcn_mfma_f32_32x32x16_bf16(kf, qf[s], sacc[t], 0, 0, 0);
        }
      }
    }
    if (doPV) {
      const u16* Vp = SM[2 + vPrev];
#pragma unroll
      for (int d2 = 0; d2 < 2; ++d2) {
        int d = d2 * 32 + (lane & 31);
#pragma unroll
        for (int ks = 0; ks < 4; ++ks) {
          bf16x8 vf = *(const bf16x8*)(Vp + (d << 6) + ((((2 * ks + h) ^ (d & 7) ^ ((d >> 3) & 7)) & 7) << 3));
          oacc[d2] = __builtin_amdgcn_mfma_f32_32x32x16_bf16(vf, pf[ks].v, oacc[d2], 0, 0, 0);
        }
      }
    }
    __builtin_amdgcn_s_setprio(0);

    if (doQK) {
      if (j == diag) {
#pragma unroll
        for (int t = 0; t < 2; ++t)
#pragma unroll
          for (int r = 0; r < 16; ++r) {
            int key = (j << 6) + 32 * t + (r & 3) + 8 * (r >> 2) + 4 * h;
            if (key > qg) sacc[t][r] = -INFINITY;
          }
      }

      float pmax = -INFINITY;
#pragma unroll
      for (int t = 0; t < 2; ++t)
#pragma unroll
        for (int r = 0; r < 16; ++r) pmax = fmaxf(pmax, sacc[t][r]);
      pmax = fmaxf(pmax, __shfl_xor(pmax, 32, 64));

      if (!__all(pmax - m <= 2.8853900817779268f)) {
        float mn = fmaxf(m, pmax);
        float alpha = exp2f(m - mn);
        m = mn;
        l *= alpha;
#pragma unroll
        for (int d2 = 0; d2 < 2; ++d2)
#pragma unroll
          for (int r = 0; r < 16; ++r) oacc[d2][r] *= alpha;
      }

      float lsum = 0.0f;
#pragma unroll
      for (int t = 0; t < 2; ++t)
#pragma unroll
        for (int r = 0; r < 16; ++r) {
          float pe = exp2f(sacc[t][r] - m);
          sacc[t][r] = pe;
          lsum += pe;
        }
      lsum += __shfl_xor(lsum, 32, 64);
      l += lsum;

#pragma unroll
      for (int t = 0; t < 2; ++t) {
#pragma unroll
        for (int kb = 0; kb < 2; ++kb) {
          int base = 8 * kb;
          unsigned A0 = cvtpk(sacc[t][base + 0], sacc[t][base + 1]);
          unsigned A2 = cvtpk(sacc[t][base + 2], sacc[t][base + 3]);
          unsigned A4 = cvtpk(sacc[t][base + 4], sacc[t][base + 5]);
          unsigned A6 = cvtpk(sacc[t][base + 6], sacc[t][base + 7]);
          unsigned S0 = (unsigned)__shfl_xor((int)(h ? A0 : A4), 32, 64);
          unsigned S2 = (unsigned)__shfl_xor((int)(h ? A2 : A6), 32, 64);
          PF& u = pf[2 * t + kb];
          u.wd[0] = h ? S0 : A0;
          u.wd[1] = h ? S2 : A2;
          u.wd[2] = h ? A4 : S0;
          u.wd[3] = h ? A6 : S2;
        }
      }
    }

    if (pre) VWRITE(vNext, vv);
    __syncthreads();
    vPrev = vCur; vCur = vNext; vNext = (vNext == 2) ? 0 : (vNext + 1);
  }

  if (myNt == nt) {
    const u16* Vp = SM[2 + vPrev];
#pragma unroll
    for (int d2 = 0; d2 < 2; ++d2) {
      int d = d2 * 32 + (lane & 31);
#pragma unroll
      for (int ks = 0; ks < 4; ++ks) {
        bf16x8 vf = *(const bf16x8*)(Vp + (d << 6) + ((((2 * ks + h) ^ (d & 7) ^ ((d >> 3) & 7)) & 7) << 3));
        oacc[d2] = __builtin_amdgcn_mfma_f32_32x32x16_bf16(vf, pf[ks].v, oacc[d2], 0, 0, 0);
      }
    }
  }
  __syncthreads();

  const float rinv = 1.0f / l;
  u16* Ob = (u16*)SM;
  const int qloc = w * 32 + (lane & 31);
#pragma unroll
  for (int d2 = 0; d2 < 2; ++d2)
#pragma unroll
    for (int r = 0; r < 16; ++r) {
      int d = d2 * 32 + (r & 3) + 8 * (r >> 2) + 4 * h;
      Ob[(qloc << 6) | (d ^ ((qloc & 7) << 3))] = f2bf(oacc[d2][r] * rinv);
    }
  __syncthreads();
#pragma unroll
  for (int it = 0; it < 4; ++it) {
    int r = (tid >> 3) + it * 64;
    int c = tid & 7;
    bf16x8 val = *(const bf16x8*)(Ob + (r << 6) + (((c ^ (r & 7)) & 7) << 3));
    int qg2 = (r < 128) ? (cA * 128 + r) : (cB * 128 + (r - 128));
    *(bf16x8*)(O + (size_t)(b * T + qg2) * 1024 + hd * 64 + c * 8) = val;
  }
}

// ---------------- host launch ----------------
extern "C" void kernel_launch(void* const* d_in, const int* in_sizes, int n_in,
                              void* d_out, int out_size, void* d_ws, size_t ws_size,
                              hipStream_t stream) {
  const float* x      = (const float*)d_in[0];
  const float* gamma1 = (const float*)d_in[1];
  const float* beta1  = (const float*)d_in[2];
  const float* Wq     = (const float*)d_in[3];
  const float* bq     = (const float*)d_in[4];
  const float* Wk     = (const float*)d_in[5];
  const float* bk     = (const float*)d_in[6];
  const float* Wv     = (const float*)d_in[7];
  const float* bv     = (const float*)d_in[8];
  const float* Wo     = (const float*)d_in[9];
  const float* bo     = (const float*)d_in[10];
  const float* gamma2 = (const float*)d_in[11];
  const float* beta2  = (const float*)d_in[12];
  const float* W1     = (const float*)d_in[13];
  const float* b1     = (const float*)d_in[14];
  const float* W2     = (const float*)d_in[15];
  const float* b2     = (const float*)d_in[16];

  char* ws = (char*)d_ws;  // 64 MB layout
  u16* WqkvT = (u16*)(ws + 0 * MB);
  u16* WoT   = (u16*)(ws + 6 * MB);
  u16* W1T   = (u16*)(ws + 8 * MB);
  u16* W2T   = (u16*)(ws + 16 * MB);
  u16* qkv   = (u16*)(ws + 24 * MB);
  u16* hb    = (u16*)(ws + 24 * MB);
  u16* xn    = (u16*)(ws + 56 * MB);
  float* bqkv = (float*)d_out;
  float* x1 = (float*)d_out;

  const int M = 4096;

  wprep<<<dim3(12292), dim3(256), 0, stream>>>(Wq, Wk, Wv, Wo, W1, W2, bq, bk, bv,
                                               WqkvT, WoT, W1T, W2T, bqkv);

  ln_kernel<<<dim3(M), dim3(256), 0, stream>>>(x, gamma1, beta1, xn);

  // merged QKV projection: 256x128 tiles, 8-wave fine-phase schedule
  gemm256<0><<<dim3(384), dim3(512), 0, stream>>>(xn, WqkvT, bqkv, qkv, M, 3072, 1024);

  attn_kernel<<<dim3(256), dim3(512), 0, stream>>>(qkv, xn);

  gemm_bt<1, 64><<<dim3(512), dim3(256), 0, stream>>>(xn, WoT, bo, x, x1, M, 1024, 1024);

  ln_kernel<<<dim3(M), dim3(256), 0, stream>>>(x1, gamma2, beta2, xn);

  // MLP1: 256x128 tiles, 8-wave fine-phase schedule, GELU epilogue
  gemm256<2><<<dim3(512), dim3(512), 0, stream>>>(xn, W1T, b1, hb, M, 4096, 1024);
  gemm_bt<1, 64><<<dim3(512), dim3(256), 0, stream>>>(hb, W2T, b2, x1, d_out, M, 1024, 4096);
}

// Round 11
// 226.390 us; speedup vs baseline: 1.0653x; 1.0653x over previous
//
#include <hip/hip_runtime.h>
#include <stdint.h>

typedef unsigned short u16;
typedef short bf16x8 __attribute__((ext_vector_type(8)));
typedef float f32x4 __attribute__((ext_vector_type(4)));
typedef float f32x16 __attribute__((ext_vector_type(16)));

#define MB (1024L*1024L)

__device__ inline u16 f2bf(float f) {
  union { float f; unsigned u; } v; v.f = f;
  unsigned r = (v.u + 0x7FFFu + ((v.u >> 16) & 1u)) >> 16;
  return (u16)r;
}

__device__ inline float bf2f(u16 u) {
  union { unsigned u; float f; } v; v.u = ((unsigned)u) << 16; return v.f;
}

__device__ inline unsigned cvtpk(float lo, float hi) {
  unsigned r;
  asm("v_cvt_pk_bf16_f32 %0, %1, %2" : "=v"(r) : "v"(lo), "v"(hi));
  return r;
}

#define GLOAD16(gptr, lptr) \
  __builtin_amdgcn_global_load_lds((__attribute__((address_space(1))) void*)(gptr), \
                                   (__attribute__((address_space(3))) void*)(lptr), 16, 0, 0)

// ---------------- merged weight prep: 6 transposes + bias concat, ONE launch ----------------
__global__ __launch_bounds__(256) void wprep(
    const float* __restrict__ Wq, const float* __restrict__ Wk,
    const float* __restrict__ Wv, const float* __restrict__ Wo,
    const float* __restrict__ W1, const float* __restrict__ W2,
    const float* __restrict__ bq, const float* __restrict__ bk,
    const float* __restrict__ bv,
    u16* __restrict__ WqkvT, u16* __restrict__ WoT,
    u16* __restrict__ W1T, u16* __restrict__ W2T, float* __restrict__ bqkv) {
  const int blk = blockIdx.x;
  const int tid = threadIdx.x;
  if (blk >= 12288) {  // bias concat (4 blocks x 256 = 1024)
    int i = (blk - 12288) * 256 + tid;
    bqkv[i] = bq[i]; bqkv[1024 + i] = bk[i]; bqkv[2048 + i] = bv[i];
    return;
  }
  const float* W; u16* WT; int K, N, tb;
  if (blk < 4096) {
    K = 1024; N = 1024;
    if (blk < 1024)      { W = Wq; WT = WqkvT;               tb = blk; }
    else if (blk < 2048) { W = Wk; WT = WqkvT + 1024 * 1024; tb = blk - 1024; }
    else if (blk < 3072) { W = Wv; WT = WqkvT + 2048 * 1024; tb = blk - 2048; }
    else                 { W = Wo; WT = WoT;                 tb = blk - 3072; }
  } else if (blk < 8192) { W = W1; WT = W1T; K = 1024; N = 4096; tb = blk - 4096; }
  else                   { W = W2; WT = W2T; K = 4096; N = 1024; tb = blk - 8192; }

  __shared__ float tile[32][33];
  const int nbn = N >> 5;
  const int bk_ = tb / nbn;
  const int bn = tb % nbn;
  const int r = tid >> 3;
  const int c4 = (tid & 7) << 2;
  const float4 v = *(const float4*)(W + (size_t)(bk_ * 32 + r) * N + bn * 32 + c4);
  tile[r][c4 + 0] = v.x; tile[r][c4 + 1] = v.y;
  tile[r][c4 + 2] = v.z; tile[r][c4 + 3] = v.w;
  __syncthreads();
  ushort4 o;
  o.x = f2bf(tile[c4 + 0][r]); o.y = f2bf(tile[c4 + 1][r]);
  o.z = f2bf(tile[c4 + 2][r]); o.w = f2bf(tile[c4 + 3][r]);
  *(ushort4*)(WT + (size_t)(bn * 32 + r) * K + bk_ * 32 + c4) = o;
}

// ---------------- LayerNorm fp32 -> bf16, D=1024, one block per row ----------------
__global__ __launch_bounds__(256) void ln_kernel(const float* __restrict__ x,
                                                 const float* __restrict__ gamma,
                                                 const float* __restrict__ beta,
                                                 u16* __restrict__ out) {
  const int row = blockIdx.x;
  const int tid = threadIdx.x;
  const float4 v = *(const float4*)(x + (size_t)row * 1024 + tid * 4);
  float s = v.x + v.y + v.z + v.w;
  float s2 = v.x * v.x + v.y * v.y + v.z * v.z + v.w * v.w;
#pragma unroll
  for (int m = 1; m < 64; m <<= 1) {
    s += __shfl_xor(s, m, 64);
    s2 += __shfl_xor(s2, m, 64);
  }
  __shared__ float red[8];
  const int w = tid >> 6;
  if ((tid & 63) == 0) { red[w] = s; red[4 + w] = s2; }
  __syncthreads();
  s = red[0] + red[1] + red[2] + red[3];
  s2 = red[4] + red[5] + red[6] + red[7];
  const float mean = s * (1.0f / 1024.0f);
  const float var = s2 * (1.0f / 1024.0f) - mean * mean;
  const float rstd = rsqrtf(var + 1e-5f);
  const float4 g = *(const float4*)(gamma + tid * 4);
  const float4 b = *(const float4*)(beta + tid * 4);
  ushort4 o;
  o.x = f2bf(g.x * (v.x - mean) * rstd + b.x);
  o.y = f2bf(g.y * (v.y - mean) * rstd + b.y);
  o.z = f2bf(g.z * (v.z - mean) * rstd + b.z);
  o.w = f2bf(g.w * (v.w - mean) * rstd + b.w);
  *(ushort4*)(out + (size_t)row * 1024 + tid * 4) = o;
}

// ---------------- GEMM: C[M,N] = A[M,K](bf16) @ BT[N,K](bf16)^T ----------------
// BK=64, dbuf, depth-2 prefetch, counted vmcnt, raw barriers, setprio; XCD-swizzled grid.
// Requires M = 4096 (nBM = 32). EPI 0: bf16=acc+bias; 1: f32=acc+bias+res; 2: bf16=gelu.
template <int EPI, int BN>
__global__ __launch_bounds__(256, (BN == 64) ? 3 : 2)
void gemm_bt(const u16* __restrict__ A, const u16* __restrict__ BT,
             const float* __restrict__ bias, const float* __restrict__ res,
             void* __restrict__ outp, int M, int N, int K) {
  constexpr int MF = (BN == 128) ? 4 : 2;
  constexpr int ACH = 4;
  constexpr int BCH = BN / 32;
  constexpr int LOADS = ACH + BCH;
  __shared__ __align__(16) u16 As[2][128 * 64];
  __shared__ __align__(16) u16 Bs[2][BN * 64];
  const int nBN = N / BN;
  const int hw = blockIdx.x;
  const int xcd = hw & 7;
  const int rr = hw >> 3;
  const int bm = xcd * 4 + rr / nBN;
  const int bn = rr % nBN;
  const int tid = threadIdx.x;
  const int lane = tid & 63;
  const int wid = tid >> 6;
  const int wm = (BN == 128) ? (wid >> 1) : wid;
  const int wn = (BN == 128) ? (wid & 1) : 0;
  const int e4 = lane >> 4;

  int abase[MF], ax[MF];
#pragma unroll
  for (int m = 0; m < MF; ++m) {
    int rowa = wm * (MF * 16) + m * 16 + (lane & 15);
    abase[m] = rowa * 64; ax[m] = rowa & 7;
  }
  int bbase[4], bx[4];
#pragma unroll
  for (int n = 0; n < 4; ++n) {
    int rowb = wn * 64 + n * 16 + (lane & 15);
    bbase[n] = rowb * 64; bx[n] = rowb & 7;
  }

  size_t ga[ACH]; int loa[ACH];
#pragma unroll
  for (int c = 0; c < ACH; ++c) {
    int idx = tid + (c << 8);
    int row = idx >> 3;
    int ch = (idx & 7) ^ (row & 7);
    ga[c] = (size_t)(bm * 128 + row) * K + (ch << 3);
    loa[c] = idx << 4;
  }
  size_t gb[BCH]; int lob[BCH];
#pragma unroll
  for (int c = 0; c < BCH; ++c) {
    int idx = tid + (c << 8);
    int row = idx >> 3;
    int ch = (idx & 7) ^ (row & 7);
    gb[c] = (size_t)(bn * BN + row) * K + (ch << 3);
    lob[c] = idx << 4;
  }

#define STAGE_G(t, bb) do { \
  _Pragma("unroll") for (int c = 0; c < ACH; ++c) \
    GLOAD16(A + ga[c] + (size_t)(t) * 64, (char*)As[bb] + loa[c]); \
  _Pragma("unroll") for (int c = 0; c < BCH; ++c) \
    GLOAD16(BT + gb[c] + (size_t)(t) * 64, (char*)Bs[bb] + lob[c]); \
} while (0)

  f32x4 acc[MF][4] = {};
  const int nt = K >> 6;

  STAGE_G(0, 0);
  STAGE_G(1, 1);

  for (int t = 0; t < nt; ++t) {
    if (t + 1 < nt) {
      asm volatile("s_waitcnt vmcnt(%0)" :: "i"(LOADS) : "memory");
    } else {
      asm volatile("s_waitcnt vmcnt(0)" ::: "memory");
    }
    __builtin_amdgcn_s_barrier();
    const u16* Ap = As[t & 1];
    const u16* Bp = Bs[t & 1];
    bf16x8 af[2][MF], bfr[2][4];
#pragma unroll
    for (int kk = 0; kk < 2; ++kk) {
#pragma unroll
      for (int m = 0; m < MF; ++m)
        af[kk][m] = *(const bf16x8*)(Ap + abase[m] + (((((kk << 2) | e4)) ^ ax[m]) << 3));
#pragma unroll
      for (int n = 0; n < 4; ++n)
        bfr[kk][n] = *(const bf16x8*)(Bp + bbase[n] + (((((kk << 2) | e4)) ^ bx[n]) << 3));
    }
    asm volatile("s_waitcnt lgkmcnt(0)" ::: "memory");
    __builtin_amdgcn_s_barrier();
    if (t + 2 < nt) STAGE_G(t + 2, t & 1);
    __builtin_amdgcn_s_setprio(1);
#pragma unroll
    for (int kk = 0; kk < 2; ++kk)
#pragma unroll
      for (int m = 0; m < MF; ++m)
#pragma unroll
        for (int n = 0; n < 4; ++n)
          acc[m][n] = __builtin_amdgcn_mfma_f32_16x16x32_bf16(af[kk][m], bfr[kk][n], acc[m][n], 0, 0, 0);
    __builtin_amdgcn_s_setprio(0);
  }
#undef STAGE_G

  const int rbase = bm * 128 + wm * (MF * 16);
  const int cbase = bn * BN + wn * 64;
#pragma unroll
  for (int m = 0; m < MF; ++m) {
#pragma unroll
    for (int n = 0; n < 4; ++n) {
      const int col = cbase + n * 16 + (lane & 15);
      const int row0 = rbase + m * 16 + ((lane >> 4) << 2);
      const float bv = bias[col];
#pragma unroll
      for (int r = 0; r < 4; ++r) {
        const int row = row0 + r;
        float v = acc[m][n][r] + bv;
        if (EPI == 1) {
          ((float*)outp)[(size_t)row * N + col] = v + res[(size_t)row * N + col];
        } else if (EPI == 2) {
          float tt = v * (1.0f + 0.044715f * v * v);
          float sg = 1.0f / (1.0f + __expf(-1.5957691216057308f * tt));
          ((u16*)outp)[(size_t)row * N + col] = f2bf(v * sg);
        } else {
          ((u16*)outp)[(size_t)row * N + col] = f2bf(v);
        }
      }
    }
  }
}

// ---------------- causal flash attention, 8-warp 32x32 swapped, 2 tiles per barrier ----------------
// QKV merged bf16 (B*T, 3072). T=2048, H=16, Dh=64. Out bf16 (B*T,1024).
// Block 512 thr; warps 0-3 -> chunk cA=p, warps 4-7 -> cB=15-p. Grid 256, XCD-pinned.
// Interval i processes tiles (2i, 2i+1): two independent QK MFMA clusters, two independent
// softmax chains (ILP hides fmax/exp latency), ONE defer-max rescale, two PV clusters,
// ONE barrier. K and V quad-buffered (64KB LDS).
__global__ __launch_bounds__(512, 2) void attn_kernel(const u16* __restrict__ QKV,
                                                      u16* __restrict__ O) {
  __shared__ __align__(16) u16 SM[8][4096];  // [0..3]=K bufs, [4..7]=V bufs; epilogue reuse
  const int T = 2048, LD = 3072;
  const int blk = blockIdx.x;
  const int xcd = blk & 7;
  const int i0 = blk >> 3;
  const int bh = xcd * 4 + (i0 & 3);
  const int p = i0 >> 2;
  const int b = bh >> 4, hd = bh & 15;
  const int tid = threadIdx.x;
  const int lane = tid & 63;
  const int w = tid >> 6;
  const int h = lane >> 5;
  const int cA = p, cB = 15 - p;
  const int myc = (w < 4) ? cA : cB;
  const int qwb = myc * 128 + (w & 3) * 32;
  const int qg = qwb + (lane & 31);
  const int diag = qwb >> 6;
  const int myNt = diag + 1;
  const int nt = 2 * cB + 2;      // even
  const int ni = nt >> 1;

  const u16* Qb = QKV + (size_t)b * T * LD + hd * 64;
  const u16* Kb = Qb + 1024;
  const u16* Vb = Qb + 2048;

  // Q fragments, pre-scaled by 0.125*log2(e)
  const float QSC = 0.18033688011112042f;
  bf16x8 qf[4];
#pragma unroll
  for (int s = 0; s < 4; ++s) {
    bf16x8 raw = *(const bf16x8*)(Qb + (size_t)qg * LD + s * 16 + h * 8);
    union { unsigned wd[4]; bf16x8 v; } u;
#pragma unroll
    for (int e = 0; e < 4; ++e)
      u.wd[e] = cvtpk(bf2f((u16)raw[2 * e]) * QSC, bf2f((u16)raw[2 * e + 1]) * QSC);
    qf[s] = u.v;
  }

  f32x16 oacc[2] = {};
  f32x16 s0[2], s1[2];
  union PF { unsigned wd[4]; bf16x8 v; } pf0[4], pf1[4];
  float m = -INFINITY, l = 0.0f;

  const int srow = tid >> 3;      // 0..63
  const int scol = tid & 7;       // 16B chunk
  const int kgc = ((scol ^ (srow & 7)) << 3);

#define VWRITE(buf, vvreg) do { \
  _Pragma("unroll") for (int e = 0; e < 8; ++e) { \
    int d = scol * 8 + e; \
    SM[4 + (buf)][(d << 6) | (srow & 7) | ((((srow >> 3) ^ e ^ scol) & 7) << 3)] = (u16)(vvreg)[e]; \
  } \
} while (0)

#define QKTILE(sv, kb) do { \
  const u16* Kp_ = SM[kb]; \
  _Pragma("unroll") for (int t = 0; t < 2; ++t) { \
    _Pragma("unroll") for (int s = 0; s < 4; ++s) { \
      int row_ = t * 32 + (lane & 31); \
      bf16x8 kf_ = *(const bf16x8*)(Kp_ + (row_ << 6) + ((((2 * s + h) ^ (row_ & 7)) & 7) << 3)); \
      sv[t] = __builtin_amdgcn_mfma_f32_32x32x16_bf16(kf_, qf[s], sv[t], 0, 0, 0); \
    } \
  } \
} while (0)

#define MASKTILE(sv, jj) do { \
  _Pragma("unroll") for (int t = 0; t < 2; ++t) \
    _Pragma("unroll") for (int r = 0; r < 16; ++r) { \
      int key_ = ((jj) << 6) + 32 * t + (r & 3) + 8 * (r >> 2) + 4 * h; \
      if (key_ > qg) sv[t][r] = -INFINITY; \
    } \
} while (0)

#define PFCONV(sv, pfv) do { \
  _Pragma("unroll") for (int t = 0; t < 2; ++t) { \
    _Pragma("unroll") for (int kb = 0; kb < 2; ++kb) { \
      int base_ = 8 * kb; \
      unsigned A0 = cvtpk(sv[t][base_ + 0], sv[t][base_ + 1]); \
      unsigned A2 = cvtpk(sv[t][base_ + 2], sv[t][base_ + 3]); \
      unsigned A4 = cvtpk(sv[t][base_ + 4], sv[t][base_ + 5]); \
      unsigned A6 = cvtpk(sv[t][base_ + 6], sv[t][base_ + 7]); \
      unsigned S0 = (unsigned)__shfl_xor((int)(h ? A0 : A4), 32, 64); \
      unsigned S2 = (unsigned)__shfl_xor((int)(h ? A2 : A6), 32, 64); \
      pfv[2 * t + kb].wd[0] = h ? S0 : A0; \
      pfv[2 * t + kb].wd[1] = h ? S2 : A2; \
      pfv[2 * t + kb].wd[2] = h ? A4 : S0; \
      pfv[2 * t + kb].wd[3] = h ? A6 : S2; \
    } \
  } \
} while (0)

#define PVTILE(pfv, vb) do { \
  const u16* Vp_ = SM[4 + (vb)]; \
  _Pragma("unroll") for (int d2 = 0; d2 < 2; ++d2) { \
    int d_ = d2 * 32 + (lane & 31); \
    _Pragma("unroll") for (int ks = 0; ks < 4; ++ks) { \
      bf16x8 vf_ = *(const bf16x8*)(Vp_ + (d_ << 6) + ((((2 * ks + h) ^ (d_ & 7) ^ ((d_ >> 3) & 7)) & 7) << 3)); \
      oacc[d2] = __builtin_amdgcn_mfma_f32_32x32x16_bf16(vf_, pfv[ks].v, oacc[d2], 0, 0, 0); \
    } \
  } \
} while (0)

  // prologue: stage tiles 0 and 1
  GLOAD16(Kb + (size_t)srow * LD + kgc, (char*)SM[0] + tid * 16);
  GLOAD16(Kb + (size_t)(64 + srow) * LD + kgc, (char*)SM[1] + tid * 16);
  {
    bf16x8 va = *(const bf16x8*)(Vb + (size_t)srow * LD + scol * 8);
    bf16x8 vb = *(const bf16x8*)(Vb + (size_t)(64 + srow) * LD + scol * 8);
    VWRITE(0, va);
    VWRITE(1, vb);
  }
  __syncthreads();

  for (int it = 0; it < ni; ++it) {
    const int j0 = 2 * it, j1 = 2 * it + 1;
    const bool pre = (it + 1 < ni);
    bf16x8 vv0, vv1;
    if (pre) {
      GLOAD16(Kb + (size_t)((j0 + 2) * 64 + srow) * LD + kgc, (char*)SM[(j0 + 2) & 3] + tid * 16);
      GLOAD16(Kb + (size_t)((j1 + 2) * 64 + srow) * LD + kgc, (char*)SM[(j1 + 2) & 3] + tid * 16);
      vv0 = *(const bf16x8*)(Vb + (size_t)((j0 + 2) * 64 + srow) * LD + scol * 8);
      vv1 = *(const bf16x8*)(Vb + (size_t)((j1 + 2) * 64 + srow) * LD + scol * 8);
    }
    const bool doQK0 = (j0 < myNt);
    const bool doQK1 = (j1 < myNt);

    if (doQK0) {
      // QK for both tiles back-to-back (independent MFMA chains)
      __builtin_amdgcn_s_setprio(1);
#pragma unroll
      for (int t = 0; t < 2; ++t) { s0[t] = (f32x16)(0.0f); s1[t] = (f32x16)(0.0f); }
      QKTILE(s0, (j0 & 3));
      if (doQK1) QKTILE(s1, (j1 & 3));
      __builtin_amdgcn_s_setprio(0);

      if (j0 == diag) MASKTILE(s0, j0);
      if (doQK1 && j1 == diag) MASKTILE(s1, j1);

      // combined max over both tiles (two independent fmax chains)
      float pm0 = -INFINITY, pm1 = -INFINITY;
#pragma unroll
      for (int t = 0; t < 2; ++t)
#pragma unroll
        for (int r = 0; r < 16; ++r) {
          pm0 = fmaxf(pm0, s0[t][r]);
          if (doQK1) pm1 = fmaxf(pm1, s1[t][r]);
        }
      float pmax = doQK1 ? fmaxf(pm0, pm1) : pm0;
      pmax = fmaxf(pmax, __shfl_xor(pmax, 32, 64));

      // ONE defer-max rescale per interval (log2 domain; p <= 2^2.885)
      if (!__all(pmax - m <= 2.8853900817779268f)) {
        float mn = fmaxf(m, pmax);
        float alpha = exp2f(m - mn);
        m = mn;
        l *= alpha;
#pragma unroll
        for (int d2 = 0; d2 < 2; ++d2)
#pragma unroll
          for (int r = 0; r < 16; ++r) oacc[d2][r] *= alpha;
      }

      // exp + sum, both tiles interleaved
      float ls0 = 0.0f, ls1 = 0.0f;
#pragma unroll
      for (int t = 0; t < 2; ++t)
#pragma unroll
        for (int r = 0; r < 16; ++r) {
          float p0 = exp2f(s0[t][r] - m);
          s0[t][r] = p0; ls0 += p0;
          if (doQK1) {
            float p1 = exp2f(s1[t][r] - m);
            s1[t][r] = p1; ls1 += p1;
          }
        }
      float lsum = doQK1 ? (ls0 + ls1) : ls0;
      lsum += __shfl_xor(lsum, 32, 64);
      l += lsum;

      PFCONV(s0, pf0);
      if (doQK1) PFCONV(s1, pf1);

      // PV for both tiles (extends K-dim; same oacc)
      __builtin_amdgcn_s_setprio(1);
      PVTILE(pf0, (j0 & 3));
      if (doQK1) PVTILE(pf1, (j1 & 3));
      __builtin_amdgcn_s_setprio(0);
    }

    // late write of next V tiles (loads issued early; HBM latency hidden under compute)
    if (pre) {
      VWRITE((j0 + 2) & 3, vv0);
      VWRITE((j1 + 2) & 3, vv1);
    }
    __syncthreads();
  }
#undef VWRITE
#undef QKTILE
#undef MASKTILE
#undef PFCONV
#undef PVTILE

  // epilogue: O = O^T / l, transpose via LDS, coalesced store
  const float rinv = 1.0f / l;
  u16* Ob = (u16*)SM;
  const int qloc = w * 32 + (lane & 31);
#pragma unroll
  for (int d2 = 0; d2 < 2; ++d2)
#pragma unroll
    for (int r = 0; r < 16; ++r) {
      int d = d2 * 32 + (r & 3) + 8 * (r >> 2) + 4 * h;
      Ob[(qloc << 6) | (d ^ ((qloc & 7) << 3))] = f2bf(oacc[d2][r] * rinv);
    }
  __syncthreads();
#pragma unroll
  for (int it = 0; it < 4; ++it) {
    int r = (tid >> 3) + it * 64;
    int c = tid & 7;
    bf16x8 val = *(const bf16x8*)(Ob + (r << 6) + (((c ^ (r & 7)) & 7) << 3));
    int qg2 = (r < 128) ? (cA * 128 + r) : (cB * 128 + (r - 128));
    *(bf16x8*)(O + (size_t)(b * T + qg2) * 1024 + hd * 64 + c * 8) = val;
  }
}

// ---------------- host launch ----------------
extern "C" void kernel_launch(void* const* d_in, const int* in_sizes, int n_in,
                              void* d_out, int out_size, void* d_ws, size_t ws_size,
                              hipStream_t stream) {
  const float* x      = (const float*)d_in[0];
  const float* gamma1 = (const float*)d_in[1];
  const float* beta1  = (const float*)d_in[2];
  const float* Wq     = (const float*)d_in[3];
  const float* bq     = (const float*)d_in[4];
  const float* Wk     = (const float*)d_in[5];
  const float* bk     = (const float*)d_in[6];
  const float* Wv     = (const float*)d_in[7];
  const float* bv     = (const float*)d_in[8];
  const float* Wo     = (const float*)d_in[9];
  const float* bo     = (const float*)d_in[10];
  const float* gamma2 = (const float*)d_in[11];
  const float* beta2  = (const float*)d_in[12];
  const float* W1     = (const float*)d_in[13];
  const float* b1     = (const float*)d_in[14];
  const float* W2     = (const float*)d_in[15];
  const float* b2     = (const float*)d_in[16];

  char* ws = (char*)d_ws;  // 64 MB layout
  u16* WqkvT = (u16*)(ws + 0 * MB);
  u16* WoT   = (u16*)(ws + 6 * MB);
  u16* W1T   = (u16*)(ws + 8 * MB);
  u16* W2T   = (u16*)(ws + 16 * MB);
  u16* qkv   = (u16*)(ws + 24 * MB);
  u16* hb    = (u16*)(ws + 24 * MB);
  u16* xn    = (u16*)(ws + 56 * MB);
  float* bqkv = (float*)d_out;
  float* x1 = (float*)d_out;

  const int M = 4096;

  wprep<<<dim3(12292), dim3(256), 0, stream>>>(Wq, Wk, Wv, Wo, W1, W2, bq, bk, bv,
                                               WqkvT, WoT, W1T, W2T, bqkv);

  ln_kernel<<<dim3(M), dim3(256), 0, stream>>>(x, gamma1, beta1, xn);

  gemm_bt<0, 128><<<dim3(768), dim3(256), 0, stream>>>(xn, WqkvT, bqkv, nullptr, qkv, M, 3072, 1024);

  attn_kernel<<<dim3(256), dim3(512), 0, stream>>>(qkv, xn);

  gemm_bt<1, 64><<<dim3(512), dim3(256), 0, stream>>>(xn, WoT, bo, x, x1, M, 1024, 1024);

  ln_kernel<<<dim3(M), dim3(256), 0, stream>>>(x1, gamma2, beta2, xn);

  gemm_bt<2, 128><<<dim3(1024), dim3(256), 0, stream>>>(xn, W1T, b1, nullptr, hb, M, 4096, 1024);
  gemm_bt<1, 64><<<dim3(512), dim3(256), 0, stream>>>(hb, W2T, b2, x1, d_out, M, 1024, 4096);
}

// Round 12
// 226.189 us; speedup vs baseline: 1.0662x; 1.0009x over previous
//
#include <hip/hip_runtime.h>
#include <stdint.h>

typedef unsigned short u16;
typedef short bf16x8 __attribute__((ext_vector_type(8)));
typedef float f32x4 __attribute__((ext_vector_type(4)));
typedef float f32x16 __attribute__((ext_vector_type(16)));

#define MB (1024L*1024L)

__device__ inline u16 f2bf(float f) {
  union { float f; unsigned u; } v; v.f = f;
  unsigned r = (v.u + 0x7FFFu + ((v.u >> 16) & 1u)) >> 16;
  return (u16)r;
}

__device__ inline float bf2f(u16 u) {
  union { unsigned u; float f; } v; v.u = ((unsigned)u) << 16; return v.f;
}

__device__ inline unsigned cvtpk(float lo, float hi) {
  unsigned r;
  asm("v_cvt_pk_bf16_f32 %0, %1, %2" : "=v"(r) : "v"(lo), "v"(hi));
  return r;
}

#define GLOAD16(gptr, lptr) \
  __builtin_amdgcn_global_load_lds((__attribute__((address_space(1))) void*)(gptr), \
                                   (__attribute__((address_space(3))) void*)(lptr), 16, 0, 0)

// ------- merged prep: 6 weight transposes + bias concat + LN1 (independent work) -------
__global__ __launch_bounds__(256) void wprep(
    const float* __restrict__ Wq, const float* __restrict__ Wk,
    const float* __restrict__ Wv, const float* __restrict__ Wo,
    const float* __restrict__ W1, const float* __restrict__ W2,
    const float* __restrict__ bq, const float* __restrict__ bk,
    const float* __restrict__ bv,
    u16* __restrict__ WqkvT, u16* __restrict__ WoT,
    u16* __restrict__ W1T, u16* __restrict__ W2T, float* __restrict__ bqkv,
    const float* __restrict__ x, const float* __restrict__ gamma1,
    const float* __restrict__ beta1, u16* __restrict__ xn) {
  const int blk = blockIdx.x;
  const int tid = threadIdx.x;
  __shared__ float tile[32][33];
  __shared__ float red[8];

  if (blk >= 12292) {  // LN1 rows (4096 blocks)
    const int row = blk - 12292;
    const float4 v = *(const float4*)(x + (size_t)row * 1024 + tid * 4);
    float s = v.x + v.y + v.z + v.w;
    float s2 = v.x * v.x + v.y * v.y + v.z * v.z + v.w * v.w;
#pragma unroll
    for (int mm = 1; mm < 64; mm <<= 1) {
      s += __shfl_xor(s, mm, 64);
      s2 += __shfl_xor(s2, mm, 64);
    }
    const int w = tid >> 6;
    if ((tid & 63) == 0) { red[w] = s; red[4 + w] = s2; }
    __syncthreads();
    s = red[0] + red[1] + red[2] + red[3];
    s2 = red[4] + red[5] + red[6] + red[7];
    const float mean = s * (1.0f / 1024.0f);
    const float var = s2 * (1.0f / 1024.0f) - mean * mean;
    const float rstd = rsqrtf(var + 1e-5f);
    const float4 g = *(const float4*)(gamma1 + tid * 4);
    const float4 bb = *(const float4*)(beta1 + tid * 4);
    ushort4 o;
    o.x = f2bf(g.x * (v.x - mean) * rstd + bb.x);
    o.y = f2bf(g.y * (v.y - mean) * rstd + bb.y);
    o.z = f2bf(g.z * (v.z - mean) * rstd + bb.z);
    o.w = f2bf(g.w * (v.w - mean) * rstd + bb.w);
    *(ushort4*)(xn + (size_t)row * 1024 + tid * 4) = o;
    return;
  }
  if (blk >= 12288) {  // bias concat
    int i = (blk - 12288) * 256 + tid;
    bqkv[i] = bq[i]; bqkv[1024 + i] = bk[i]; bqkv[2048 + i] = bv[i];
    return;
  }
  const float* W; u16* WT; int K, N, tb;
  if (blk < 4096) {
    K = 1024; N = 1024;
    if (blk < 1024)      { W = Wq; WT = WqkvT;               tb = blk; }
    else if (blk < 2048) { W = Wk; WT = WqkvT + 1024 * 1024; tb = blk - 1024; }
    else if (blk < 3072) { W = Wv; WT = WqkvT + 2048 * 1024; tb = blk - 2048; }
    else                 { W = Wo; WT = WoT;                 tb = blk - 3072; }
  } else if (blk < 8192) { W = W1; WT = W1T; K = 1024; N = 4096; tb = blk - 4096; }
  else                   { W = W2; WT = W2T; K = 4096; N = 1024; tb = blk - 8192; }

  const int nbn = N >> 5;
  const int bk_ = tb / nbn;
  const int bn = tb % nbn;
  const int r = tid >> 3;
  const int c4 = (tid & 7) << 2;
  const float4 v = *(const float4*)(W + (size_t)(bk_ * 32 + r) * N + bn * 32 + c4);
  tile[r][c4 + 0] = v.x; tile[r][c4 + 1] = v.y;
  tile[r][c4 + 2] = v.z; tile[r][c4 + 3] = v.w;
  __syncthreads();
  ushort4 o;
  o.x = f2bf(tile[c4 + 0][r]); o.y = f2bf(tile[c4 + 1][r]);
  o.z = f2bf(tile[c4 + 2][r]); o.w = f2bf(tile[c4 + 3][r]);
  *(ushort4*)(WT + (size_t)(bn * 32 + r) * K + bk_ * 32 + c4) = o;
}

// ---------------- LayerNorm fp32 -> bf16 (LN2) ----------------
__global__ __launch_bounds__(256) void ln_kernel(const float* __restrict__ x,
                                                 const float* __restrict__ gamma,
                                                 const float* __restrict__ beta,
                                                 u16* __restrict__ out) {
  const int row = blockIdx.x;
  const int tid = threadIdx.x;
  const float4 v = *(const float4*)(x + (size_t)row * 1024 + tid * 4);
  float s = v.x + v.y + v.z + v.w;
  float s2 = v.x * v.x + v.y * v.y + v.z * v.z + v.w * v.w;
#pragma unroll
  for (int m = 1; m < 64; m <<= 1) {
    s += __shfl_xor(s, m, 64);
    s2 += __shfl_xor(s2, m, 64);
  }
  __shared__ float red[8];
  const int w = tid >> 6;
  if ((tid & 63) == 0) { red[w] = s; red[4 + w] = s2; }
  __syncthreads();
  s = red[0] + red[1] + red[2] + red[3];
  s2 = red[4] + red[5] + red[6] + red[7];
  const float mean = s * (1.0f / 1024.0f);
  const float var = s2 * (1.0f / 1024.0f) - mean * mean;
  const float rstd = rsqrtf(var + 1e-5f);
  const float4 g = *(const float4*)(gamma + tid * 4);
  const float4 b = *(const float4*)(beta + tid * 4);
  ushort4 o;
  o.x = f2bf(g.x * (v.x - mean) * rstd + b.x);
  o.y = f2bf(g.y * (v.y - mean) * rstd + b.y);
  o.z = f2bf(g.z * (v.z - mean) * rstd + b.z);
  o.w = f2bf(g.w * (v.w - mean) * rstd + b.w);
  *(ushort4*)(out + (size_t)row * 1024 + tid * 4) = o;
}

// ---------------- GEMM: C[M,N] = A[M,K](bf16) @ BT[N,K](bf16)^T ----------------
// BK=64, dbuf, depth-2 prefetch, counted vmcnt, raw barriers, setprio; XCD-swizzled grid.
template <int EPI, int BN>
__global__ __launch_bounds__(256, (BN == 64) ? 3 : 2)
void gemm_bt(const u16* __restrict__ A, const u16* __restrict__ BT,
             const float* __restrict__ bias, const float* __restrict__ res,
             void* __restrict__ outp, int M, int N, int K) {
  constexpr int MF = (BN == 128) ? 4 : 2;
  constexpr int ACH = 4;
  constexpr int BCH = BN / 32;
  constexpr int LOADS = ACH + BCH;
  __shared__ __align__(16) u16 As[2][128 * 64];
  __shared__ __align__(16) u16 Bs[2][BN * 64];
  const int nBN = N / BN;
  const int hw = blockIdx.x;
  const int xcd = hw & 7;
  const int rr = hw >> 3;
  const int bm = xcd * 4 + rr / nBN;
  const int bn = rr % nBN;
  const int tid = threadIdx.x;
  const int lane = tid & 63;
  const int wid = tid >> 6;
  const int wm = (BN == 128) ? (wid >> 1) : wid;
  const int wn = (BN == 128) ? (wid & 1) : 0;
  const int e4 = lane >> 4;

  int abase[MF], ax[MF];
#pragma unroll
  for (int m = 0; m < MF; ++m) {
    int rowa = wm * (MF * 16) + m * 16 + (lane & 15);
    abase[m] = rowa * 64; ax[m] = rowa & 7;
  }
  int bbase[4], bx[4];
#pragma unroll
  for (int n = 0; n < 4; ++n) {
    int rowb = wn * 64 + n * 16 + (lane & 15);
    bbase[n] = rowb * 64; bx[n] = rowb & 7;
  }

  size_t ga[ACH]; int loa[ACH];
#pragma unroll
  for (int c = 0; c < ACH; ++c) {
    int idx = tid + (c << 8);
    int row = idx >> 3;
    int ch = (idx & 7) ^ (row & 7);
    ga[c] = (size_t)(bm * 128 + row) * K + (ch << 3);
    loa[c] = idx << 4;
  }
  size_t gb[BCH]; int lob[BCH];
#pragma unroll
  for (int c = 0; c < BCH; ++c) {
    int idx = tid + (c << 8);
    int row = idx >> 3;
    int ch = (idx & 7) ^ (row & 7);
    gb[c] = (size_t)(bn * BN + row) * K + (ch << 3);
    lob[c] = idx << 4;
  }

#define STAGE_G(t, bb) do { \
  _Pragma("unroll") for (int c = 0; c < ACH; ++c) \
    GLOAD16(A + ga[c] + (size_t)(t) * 64, (char*)As[bb] + loa[c]); \
  _Pragma("unroll") for (int c = 0; c < BCH; ++c) \
    GLOAD16(BT + gb[c] + (size_t)(t) * 64, (char*)Bs[bb] + lob[c]); \
} while (0)

  f32x4 acc[MF][4] = {};
  const int nt = K >> 6;

  STAGE_G(0, 0);
  STAGE_G(1, 1);

  for (int t = 0; t < nt; ++t) {
    if (t + 1 < nt) {
      asm volatile("s_waitcnt vmcnt(%0)" :: "i"(LOADS) : "memory");
    } else {
      asm volatile("s_waitcnt vmcnt(0)" ::: "memory");
    }
    __builtin_amdgcn_s_barrier();
    const u16* Ap = As[t & 1];
    const u16* Bp = Bs[t & 1];
    bf16x8 af[2][MF], bfr[2][4];
#pragma unroll
    for (int kk = 0; kk < 2; ++kk) {
#pragma unroll
      for (int m = 0; m < MF; ++m)
        af[kk][m] = *(const bf16x8*)(Ap + abase[m] + (((((kk << 2) | e4)) ^ ax[m]) << 3));
#pragma unroll
      for (int n = 0; n < 4; ++n)
        bfr[kk][n] = *(const bf16x8*)(Bp + bbase[n] + (((((kk << 2) | e4)) ^ bx[n]) << 3));
    }
    asm volatile("s_waitcnt lgkmcnt(0)" ::: "memory");
    __builtin_amdgcn_s_barrier();
    if (t + 2 < nt) STAGE_G(t + 2, t & 1);
    __builtin_amdgcn_s_setprio(1);
#pragma unroll
    for (int kk = 0; kk < 2; ++kk)
#pragma unroll
      for (int m = 0; m < MF; ++m)
#pragma unroll
        for (int n = 0; n < 4; ++n)
          acc[m][n] = __builtin_amdgcn_mfma_f32_16x16x32_bf16(af[kk][m], bfr[kk][n], acc[m][n], 0, 0, 0);
    __builtin_amdgcn_s_setprio(0);
  }
#undef STAGE_G

  const int rbase = bm * 128 + wm * (MF * 16);
  const int cbase = bn * BN + wn * 64;
#pragma unroll
  for (int m = 0; m < MF; ++m) {
#pragma unroll
    for (int n = 0; n < 4; ++n) {
      const int col = cbase + n * 16 + (lane & 15);
      const int row0 = rbase + m * 16 + ((lane >> 4) << 2);
      const float bv = bias[col];
#pragma unroll
      for (int r = 0; r < 4; ++r) {
        const int row = row0 + r;
        float v = acc[m][n][r] + bv;
        if (EPI == 1) {
          ((float*)outp)[(size_t)row * N + col] = v + res[(size_t)row * N + col];
        } else if (EPI == 2) {
          float tt = v * (1.0f + 0.044715f * v * v);
          float sg = 1.0f / (1.0f + __expf(-1.5957691216057308f * tt));
          ((u16*)outp)[(size_t)row * N + col] = f2bf(v * sg);
        } else {
          ((u16*)outp)[(size_t)row * N + col] = f2bf(v);
        }
      }
    }
  }
}

// -------- causal flash attention: 8-warp, 64-row chunks, K-parity split, grid 512 --------
// QKV merged bf16 (B*T,3072). Block: chunks cA=p (warps 0-3), cB=31-p (warps 4-7).
// Within a chunk's 4 warps: (w&1) = row half (32 rows), ((w>>1)&1) = K-tile parity.
// Per barrier interval: par0 computes tile j0, par1 computes tile j1 concurrently.
// End: parity pairs merge online-softmax states in LDS. 2 blocks/CU co-resident.
__global__ __launch_bounds__(512, 2) void attn_kernel(const u16* __restrict__ QKV,
                                                      u16* __restrict__ O) {
  __shared__ __align__(16) u16 SM[8][4096];  // [0..3] K bufs, [4..7] V bufs; reused for merge
  const int T = 2048, LD = 3072;
  const int blk = blockIdx.x;
  const int xcd = blk & 7;
  const int i = blk >> 3;                 // 0..63
  const int bh = xcd * 4 + (i & 3);       // 4 bh per XCD
  const int p = i >> 2;                   // 0..15
  const int b = bh >> 4, hd = bh & 15;
  const int tid = threadIdx.x;
  const int lane = tid & 63;
  const int w = tid >> 6;
  const int h = lane >> 5;
  const int grp = w >> 2;                 // 0 -> cA, 1 -> cB
  const int wr = w & 1;                   // row half within chunk
  const int par = (w >> 1) & 1;           // K-tile parity
  const int cA = p, cB = 31 - p;
  const int myc = grp ? cB : cA;
  const int qg = myc * 64 + wr * 32 + (lane & 31);
  const int myNt = myc + 1;               // tiles this chunk needs
  const int nt = cB + 1;                  // tiles staged (covers cB)
  const int ni = (nt + 1) >> 1;

  const u16* Qb = QKV + (size_t)b * T * LD + hd * 64;
  const u16* Kb = Qb + 1024;
  const u16* Vb = Qb + 2048;

  // Q fragments, pre-scaled by 0.125*log2(e)
  const float QSC = 0.18033688011112042f;
  bf16x8 qf[4];
#pragma unroll
  for (int s = 0; s < 4; ++s) {
    bf16x8 raw = *(const bf16x8*)(Qb + (size_t)qg * LD + s * 16 + h * 8);
    union { unsigned wd[4]; bf16x8 v; } u;
#pragma unroll
    for (int e = 0; e < 4; ++e)
      u.wd[e] = cvtpk(bf2f((u16)raw[2 * e]) * QSC, bf2f((u16)raw[2 * e + 1]) * QSC);
    qf[s] = u.v;
  }

  f32x16 oacc[2] = {};
  f32x16 sacc[2];
  union PF { unsigned wd[4]; bf16x8 v; } pf[4];
  float m = -INFINITY, l = 0.0f;

  const int srow = tid >> 3;      // 0..63
  const int scol = tid & 7;       // 16B chunk
  const int kgc = ((scol ^ (srow & 7)) << 3);

#define VWRITE(buf, vvreg) do { \
  _Pragma("unroll") for (int e = 0; e < 8; ++e) { \
    int d = scol * 8 + e; \
    SM[4 + (buf)][(d << 6) | (srow & 7) | ((((srow >> 3) ^ e ^ scol) & 7) << 3)] = (u16)(vvreg)[e]; \
  } \
} while (0)

  // prologue: stage tiles 0 and 1
  GLOAD16(Kb + (size_t)srow * LD + kgc, (char*)SM[0] + tid * 16);
  GLOAD16(Kb + (size_t)(64 + srow) * LD + kgc, (char*)SM[1] + tid * 16);
  {
    bf16x8 va = *(const bf16x8*)(Vb + (size_t)srow * LD + scol * 8);
    bf16x8 vb = *(const bf16x8*)(Vb + (size_t)(64 + srow) * LD + scol * 8);
    VWRITE(0, va);
    VWRITE(1, vb);
  }
  __syncthreads();

  for (int it = 0; it < ni; ++it) {
    const int j0 = 2 * it, j1 = j0 + 1;
    const bool pre0 = (j0 + 2 < nt);
    const bool pre1 = (j1 + 2 < nt);
    bf16x8 vv0, vv1;
    if (pre0) {
      GLOAD16(Kb + (size_t)((j0 + 2) * 64 + srow) * LD + kgc, (char*)SM[(j0 + 2) & 3] + tid * 16);
      vv0 = *(const bf16x8*)(Vb + (size_t)((j0 + 2) * 64 + srow) * LD + scol * 8);
    }
    if (pre1) {
      GLOAD16(Kb + (size_t)((j1 + 2) * 64 + srow) * LD + kgc, (char*)SM[(j1 + 2) & 3] + tid * 16);
      vv1 = *(const bf16x8*)(Vb + (size_t)((j1 + 2) * 64 + srow) * LD + scol * 8);
    }

    const int jm = j0 + par;   // this warp's tile (its parity)
    if (jm < myNt) {
      // S'^T = K * Q'^T (log2-domain)
      const u16* Kp = SM[jm & 3];
      __builtin_amdgcn_s_setprio(1);
#pragma unroll
      for (int t = 0; t < 2; ++t) {
#pragma unroll
        for (int r = 0; r < 16; ++r) sacc[t][r] = 0.0f;
#pragma unroll
        for (int s = 0; s < 4; ++s) {
          int row = t * 32 + (lane & 31);
          bf16x8 kf = *(const bf16x8*)(Kp + (row << 6) + ((((2 * s + h) ^ (row & 7)) & 7) << 3));
          sacc[t] = __builtin_amdgcn_mfma_f32_32x32x16_bf16(kf, qf[s], sacc[t], 0, 0, 0);
        }
      }
      __builtin_amdgcn_s_setprio(0);

      if (jm == myc) {  // diagonal tile: causal mask
#pragma unroll
        for (int t = 0; t < 2; ++t)
#pragma unroll
          for (int r = 0; r < 16; ++r) {
            int key = (jm << 6) + 32 * t + (r & 3) + 8 * (r >> 2) + 4 * h;
            if (key > qg) sacc[t][r] = -INFINITY;
          }
      }

      float pmax = -INFINITY;
#pragma unroll
      for (int t = 0; t < 2; ++t)
#pragma unroll
        for (int r = 0; r < 16; ++r) pmax = fmaxf(pmax, sacc[t][r]);
      pmax = fmaxf(pmax, __shfl_xor(pmax, 32, 64));

      // defer-max (log2 domain; p <= 2^2.885 = e^2)
      if (!__all(pmax - m <= 2.8853900817779268f)) {
        float mn = fmaxf(m, pmax);
        float alpha = exp2f(m - mn);
        m = mn;
        l *= alpha;
#pragma unroll
        for (int d2 = 0; d2 < 2; ++d2)
#pragma unroll
          for (int r = 0; r < 16; ++r) oacc[d2][r] *= alpha;
      }

      float lsum = 0.0f;
#pragma unroll
      for (int t = 0; t < 2; ++t)
#pragma unroll
        for (int r = 0; r < 16; ++r) {
          float pe = exp2f(sacc[t][r] - m);
          sacc[t][r] = pe;
          lsum += pe;
        }
      lsum += __shfl_xor(lsum, 32, 64);
      l += lsum;

      // P^T B-fragments (cvt_pk + half swap)
#pragma unroll
      for (int t = 0; t < 2; ++t) {
#pragma unroll
        for (int kb = 0; kb < 2; ++kb) {
          int base = 8 * kb;
          unsigned A0 = cvtpk(sacc[t][base + 0], sacc[t][base + 1]);
          unsigned A2 = cvtpk(sacc[t][base + 2], sacc[t][base + 3]);
          unsigned A4 = cvtpk(sacc[t][base + 4], sacc[t][base + 5]);
          unsigned A6 = cvtpk(sacc[t][base + 6], sacc[t][base + 7]);
          unsigned S0 = (unsigned)__shfl_xor((int)(h ? A0 : A4), 32, 64);
          unsigned S2 = (unsigned)__shfl_xor((int)(h ? A2 : A6), 32, 64);
          PF& u = pf[2 * t + kb];
          u.wd[0] = h ? S0 : A0;
          u.wd[1] = h ? S2 : A2;
          u.wd[2] = h ? A4 : S0;
          u.wd[3] = h ? A6 : S2;
        }
      }

      // O^T += V^T * P^T
      const u16* Vp = SM[4 + (jm & 3)];
      __builtin_amdgcn_s_setprio(1);
#pragma unroll
      for (int d2 = 0; d2 < 2; ++d2) {
        int d = d2 * 32 + (lane & 31);
#pragma unroll
        for (int ks = 0; ks < 4; ++ks) {
          bf16x8 vf = *(const bf16x8*)(Vp + (d << 6) + ((((2 * ks + h) ^ (d & 7) ^ ((d >> 3) & 7)) & 7) << 3));
          oacc[d2] = __builtin_amdgcn_mfma_f32_32x32x16_bf16(vf, pf[ks].v, oacc[d2], 0, 0, 0);
        }
      }
      __builtin_amdgcn_s_setprio(0);
    }

    // late V writes (loads issued early; latency hidden under compute)
    if (pre0) VWRITE((j0 + 2) & 3, vv0);
    if (pre1) VWRITE((j1 + 2) & 3, vv1);
    __syncthreads();
  }
#undef VWRITE

  // ---- merge parity pairs (same 32 rows, complementary K-tiles) via LDS ----
  float* dumpO = (float*)SM;                      // 32KB: slot(0..3) x lane(0..63) x 32 f32
  float* dumpML = (float*)((char*)SM + 32768);    // 2KB
  u16* Ob = (u16*)((char*)SM + 40960);            // 16KB: [128 rows][64 d], swizzled
  const int slot = grp * 2 + wr;                  // 0..3
  if (par == 1) {
    float* dO = dumpO + (slot * 64 + lane) * 32;
#pragma unroll
    for (int d2 = 0; d2 < 2; ++d2)
#pragma unroll
      for (int r = 0; r < 16; ++r) dO[d2 * 16 + r] = oacc[d2][r];
    dumpML[(slot * 64 + lane) * 2 + 0] = m;
    dumpML[(slot * 64 + lane) * 2 + 1] = l;
  }
  __syncthreads();
  if (par == 0) {
    const float* dO = dumpO + (slot * 64 + lane) * 32;
    float m1 = dumpML[(slot * 64 + lane) * 2 + 0];
    float l1 = dumpML[(slot * 64 + lane) * 2 + 1];
    float mM = fmaxf(m, m1);
    float a0 = exp2f(m - mM), a1 = exp2f(m1 - mM);
    float lm = l * a0 + l1 * a1;
    float rinv = 1.0f / lm;
    const int row = slot * 32 + (lane & 31);      // 0..127 local
#pragma unroll
    for (int d2 = 0; d2 < 2; ++d2)
#pragma unroll
      for (int r = 0; r < 16; ++r) {
        float ov = (oacc[d2][r] * a0 + dO[d2 * 16 + r] * a1) * rinv;
        int d = d2 * 32 + (r & 3) + 8 * (r >> 2) + 4 * h;
        Ob[(row << 6) | (d ^ ((row & 7) << 3))] = f2bf(ov);
      }
  }
  __syncthreads();
#pragma unroll
  for (int it2 = 0; it2 < 2; ++it2) {
    int r = (tid >> 3) + it2 * 64;                // 0..127
    int c = tid & 7;
    bf16x8 val = *(const bf16x8*)(Ob + (r << 6) + (((c ^ (r & 7)) & 7) << 3));
    int qg2 = ((r < 64) ? cA : cB) * 64 + (r & 63);
    *(bf16x8*)(O + (size_t)(b * T + qg2) * 1024 + hd * 64 + c * 8) = val;
  }
}

// ---------------- host launch ----------------
extern "C" void kernel_launch(void* const* d_in, const int* in_sizes, int n_in,
                              void* d_out, int out_size, void* d_ws, size_t ws_size,
                              hipStream_t stream) {
  const float* x      = (const float*)d_in[0];
  const float* gamma1 = (const float*)d_in[1];
  const float* beta1  = (const float*)d_in[2];
  const float* Wq     = (const float*)d_in[3];
  const float* bq     = (const float*)d_in[4];
  const float* Wk     = (const float*)d_in[5];
  const float* bk     = (const float*)d_in[6];
  const float* Wv     = (const float*)d_in[7];
  const float* bv     = (const float*)d_in[8];
  const float* Wo     = (const float*)d_in[9];
  const float* bo     = (const float*)d_in[10];
  const float* gamma2 = (const float*)d_in[11];
  const float* beta2  = (const float*)d_in[12];
  const float* W1     = (const float*)d_in[13];
  const float* b1     = (const float*)d_in[14];
  const float* W2     = (const float*)d_in[15];
  const float* b2     = (const float*)d_in[16];

  char* ws = (char*)d_ws;  // 64 MB layout
  u16* WqkvT = (u16*)(ws + 0 * MB);
  u16* WoT   = (u16*)(ws + 6 * MB);
  u16* W1T   = (u16*)(ws + 8 * MB);
  u16* W2T   = (u16*)(ws + 16 * MB);
  u16* qkv   = (u16*)(ws + 24 * MB);
  u16* hb    = (u16*)(ws + 24 * MB);
  u16* xn    = (u16*)(ws + 56 * MB);
  float* bqkv = (float*)d_out;
  float* x1 = (float*)d_out;

  const int M = 4096;

  // prep: transposes + bias concat + LN1, one launch
  wprep<<<dim3(16388), dim3(256), 0, stream>>>(Wq, Wk, Wv, Wo, W1, W2, bq, bk, bv,
                                               WqkvT, WoT, W1T, W2T, bqkv,
                                               x, gamma1, beta1, xn);

  gemm_bt<0, 128><<<dim3(768), dim3(256), 0, stream>>>(xn, WqkvT, bqkv, nullptr, qkv, M, 3072, 1024);

  attn_kernel<<<dim3(512), dim3(512), 0, stream>>>(qkv, xn);

  gemm_bt<1, 64><<<dim3(512), dim3(256), 0, stream>>>(xn, WoT, bo, x, x1, M, 1024, 1024);

  ln_kernel<<<dim3(M), dim3(256), 0, stream>>>(x1, gamma2, beta2, xn);

  gemm_bt<2, 128><<<dim3(1024), dim3(256), 0, stream>>>(xn, W1T, b1, nullptr, hb, M, 4096, 1024);
  gemm_bt<1, 64><<<dim3(512), dim3(256), 0, stream>>>(hb, W2T, b2, x1, d_out, M, 1024, 4096);
}

// Round 13
// 219.732 us; speedup vs baseline: 1.0975x; 1.0294x over previous
//
#include <hip/hip_runtime.h>
#include <stdint.h>

typedef unsigned short u16;
typedef short bf16x8 __attribute__((ext_vector_type(8)));
typedef float f32x4 __attribute__((ext_vector_type(4)));
typedef float f32x16 __attribute__((ext_vector_type(16)));

#define MB (1024L*1024L)

__device__ inline u16 f2bf(float f) {
  union { float f; unsigned u; } v; v.f = f;
  unsigned r = (v.u + 0x7FFFu + ((v.u >> 16) & 1u)) >> 16;
  return (u16)r;
}

__device__ inline float bf2f(u16 u) {
  union { unsigned u; float f; } v; v.u = ((unsigned)u) << 16; return v.f;
}

__device__ inline unsigned cvtpk(float lo, float hi) {
  unsigned r;
  asm("v_cvt_pk_bf16_f32 %0, %1, %2" : "=v"(r) : "v"(lo), "v"(hi));
  return r;
}

#define GLOAD16(gptr, lptr) \
  __builtin_amdgcn_global_load_lds((__attribute__((address_space(1))) void*)(gptr), \
                                   (__attribute__((address_space(3))) void*)(lptr), 16, 0, 0)

// ------- merged prep: 6 weight transposes + bias concat + LN1 -------
__global__ __launch_bounds__(256) void wprep(
    const float* __restrict__ Wq, const float* __restrict__ Wk,
    const float* __restrict__ Wv, const float* __restrict__ Wo,
    const float* __restrict__ W1, const float* __restrict__ W2,
    const float* __restrict__ bq, const float* __restrict__ bk,
    const float* __restrict__ bv,
    u16* __restrict__ WqkvT, u16* __restrict__ WoT,
    u16* __restrict__ W1T, u16* __restrict__ W2T, float* __restrict__ bqkv,
    const float* __restrict__ x, const float* __restrict__ gamma1,
    const float* __restrict__ beta1, u16* __restrict__ xn) {
  const int blk = blockIdx.x;
  const int tid = threadIdx.x;
  __shared__ float tile[32][33];
  __shared__ float red[8];

  if (blk >= 12292) {  // LN1 rows (4096 blocks)
    const int row = blk - 12292;
    const float4 v = *(const float4*)(x + (size_t)row * 1024 + tid * 4);
    float s = v.x + v.y + v.z + v.w;
    float s2 = v.x * v.x + v.y * v.y + v.z * v.z + v.w * v.w;
#pragma unroll
    for (int mm = 1; mm < 64; mm <<= 1) {
      s += __shfl_xor(s, mm, 64);
      s2 += __shfl_xor(s2, mm, 64);
    }
    const int w = tid >> 6;
    if ((tid & 63) == 0) { red[w] = s; red[4 + w] = s2; }
    __syncthreads();
    s = red[0] + red[1] + red[2] + red[3];
    s2 = red[4] + red[5] + red[6] + red[7];
    const float mean = s * (1.0f / 1024.0f);
    const float var = s2 * (1.0f / 1024.0f) - mean * mean;
    const float rstd = rsqrtf(var + 1e-5f);
    const float4 g = *(const float4*)(gamma1 + tid * 4);
    const float4 bb = *(const float4*)(beta1 + tid * 4);
    ushort4 o;
    o.x = f2bf(g.x * (v.x - mean) * rstd + bb.x);
    o.y = f2bf(g.y * (v.y - mean) * rstd + bb.y);
    o.z = f2bf(g.z * (v.z - mean) * rstd + bb.z);
    o.w = f2bf(g.w * (v.w - mean) * rstd + bb.w);
    *(ushort4*)(xn + (size_t)row * 1024 + tid * 4) = o;
    return;
  }
  if (blk >= 12288) {  // bias concat
    int i = (blk - 12288) * 256 + tid;
    bqkv[i] = bq[i]; bqkv[1024 + i] = bk[i]; bqkv[2048 + i] = bv[i];
    return;
  }
  const float* W; u16* WT; int K, N, tb;
  if (blk < 4096) {
    K = 1024; N = 1024;
    if (blk < 1024)      { W = Wq; WT = WqkvT;               tb = blk; }
    else if (blk < 2048) { W = Wk; WT = WqkvT + 1024 * 1024; tb = blk - 1024; }
    else if (blk < 3072) { W = Wv; WT = WqkvT + 2048 * 1024; tb = blk - 2048; }
    else                 { W = Wo; WT = WoT;                 tb = blk - 3072; }
  } else if (blk < 8192) { W = W1; WT = W1T; K = 1024; N = 4096; tb = blk - 4096; }
  else                   { W = W2; WT = W2T; K = 4096; N = 1024; tb = blk - 8192; }

  const int nbn = N >> 5;
  const int bk_ = tb / nbn;
  const int bn = tb % nbn;
  const int r = tid >> 3;
  const int c4 = (tid & 7) << 2;
  const float4 v = *(const float4*)(W + (size_t)(bk_ * 32 + r) * N + bn * 32 + c4);
  tile[r][c4 + 0] = v.x; tile[r][c4 + 1] = v.y;
  tile[r][c4 + 2] = v.z; tile[r][c4 + 3] = v.w;
  __syncthreads();
  ushort4 o;
  o.x = f2bf(tile[c4 + 0][r]); o.y = f2bf(tile[c4 + 1][r]);
  o.z = f2bf(tile[c4 + 2][r]); o.w = f2bf(tile[c4 + 3][r]);
  *(ushort4*)(WT + (size_t)(bn * 32 + r) * K + bk_ * 32 + c4) = o;
}

// ---------------- LayerNorm fp32 -> bf16 (LN2) ----------------
__global__ __launch_bounds__(256) void ln_kernel(const float* __restrict__ x,
                                                 const float* __restrict__ gamma,
                                                 const float* __restrict__ beta,
                                                 u16* __restrict__ out) {
  const int row = blockIdx.x;
  const int tid = threadIdx.x;
  const float4 v = *(const float4*)(x + (size_t)row * 1024 + tid * 4);
  float s = v.x + v.y + v.z + v.w;
  float s2 = v.x * v.x + v.y * v.y + v.z * v.z + v.w * v.w;
#pragma unroll
  for (int m = 1; m < 64; m <<= 1) {
    s += __shfl_xor(s, m, 64);
    s2 += __shfl_xor(s2, m, 64);
  }
  __shared__ float red[8];
  const int w = tid >> 6;
  if ((tid & 63) == 0) { red[w] = s; red[4 + w] = s2; }
  __syncthreads();
  s = red[0] + red[1] + red[2] + red[3];
  s2 = red[4] + red[5] + red[6] + red[7];
  const float mean = s * (1.0f / 1024.0f);
  const float var = s2 * (1.0f / 1024.0f) - mean * mean;
  const float rstd = rsqrtf(var + 1e-5f);
  const float4 g = *(const float4*)(gamma + tid * 4);
  const float4 b = *(const float4*)(beta + tid * 4);
  ushort4 o;
  o.x = f2bf(g.x * (v.x - mean) * rstd + b.x);
  o.y = f2bf(g.y * (v.y - mean) * rstd + b.y);
  o.z = f2bf(g.z * (v.z - mean) * rstd + b.z);
  o.w = f2bf(g.w * (v.w - mean) * rstd + b.w);
  *(ushort4*)(out + (size_t)row * 1024 + tid * 4) = o;
}

// ---- GEMM 256x256, 8 waves, 4 quadrant-phases/K-tile, counted vmcnt(4), dbuf ----
// C[M,N] = A[M,K] @ BT[N,K]^T. BK=64. Grid = (M/256)*(N/256), XCD-swizzled (M=4096).
// Staging order per tile t: p1 A-lo(t+1), p2 A-hi(t+1), p3 B-lo(t+2), p4 B-hi(t+2);
// targets verified free by quadrant consumption order. EPI 0: bf16+bias; 2: gelu.
template <int EPI>
__global__ __launch_bounds__(512, 1)
void gemm256sq(const u16* __restrict__ A, const u16* __restrict__ BT,
               const float* __restrict__ bias, void* __restrict__ outp,
               int M, int N, int K) {
  __shared__ __align__(16) u16 As[2][256 * 64];  // 64KB
  __shared__ __align__(16) u16 Bs[2][256 * 64];  // 64KB
  const int nBN = N >> 8;
  const int blk = blockIdx.x;
  const int xcd = blk & 7;
  const int rr = blk >> 3;
  const int bm = xcd * 2 + rr / nBN;
  const int bn = rr % nBN;
  const int tid = threadIdx.x;
  const int lane = tid & 63;
  const int wid = tid >> 6;
  const int wm = wid >> 2;   // 0..1 -> 128 rows
  const int wn = wid & 3;    // 0..3 -> 64 cols
  const int e4 = lane >> 4;
  const int l15 = lane & 15;
  const int sx = l15 & 7;    // swizzle key (row&7 for all frag rows)

  const int aoffb = (wm * 128 + l15) * 64;
  const int boffb = (wn * 64 + l15) * 64;
  const int ch0 = ((e4 ^ sx) & 7) << 3;
  const int ch1 = (((4 | e4) ^ sx) & 7) << 3;

  size_t gA[2], gB[2]; int lo[2];
#pragma unroll
  for (int c = 0; c < 2; ++c) {
    int idx = tid + (c << 9);
    int rowl = idx >> 3;              // 0..127
    int chg = ((idx & 7) ^ (rowl & 7)) << 3;
    gA[c] = (size_t)(bm * 256 + rowl) * K + chg;
    gB[c] = (size_t)(bn * 256 + rowl) * K + chg;
    lo[c] = idx << 4;
  }
  const size_t hK = (size_t)128 * K;

#define STG_A(tt, h) do { _Pragma("unroll") for (int c = 0; c < 2; ++c) \
  GLOAD16(A + gA[c] + (size_t)(h) * hK + (size_t)(tt) * 64, (char*)As[(tt) & 1] + (h) * 16384 + lo[c]); } while (0)
#define STG_B(tt, h) do { _Pragma("unroll") for (int c = 0; c < 2; ++c) \
  GLOAD16(BT + gB[c] + (size_t)(h) * hK + (size_t)(tt) * 64, (char*)Bs[(tt) & 1] + (h) * 16384 + lo[c]); } while (0)

  f32x4 acc[8][4] = {};
  const int nt = K >> 6;

  // prologue: tile0 fully + B(1); wait tile0 (4 = B(1)'s loads outstanding)
  STG_A(0, 0); STG_A(0, 1); STG_B(0, 0); STG_B(0, 1);
  STG_B(1, 0); STG_B(1, 1);
  asm volatile("s_waitcnt vmcnt(4)" ::: "memory");
  __builtin_amdgcn_s_barrier();

  for (int t = 0; t < nt; ++t) {
    const u16* Ap = As[t & 1];
    const u16* Bp = Bs[t & 1];
    bf16x8 a[2][4], b01[2][2], b23[2][2];

    // ---- p1: quadrant (mh0, n01)
#pragma unroll
    for (int mm = 0; mm < 4; ++mm) {
      a[0][mm] = *(const bf16x8*)(Ap + aoffb + mm * 1024 + ch0);
      a[1][mm] = *(const bf16x8*)(Ap + aoffb + mm * 1024 + ch1);
    }
#pragma unroll
    for (int nn = 0; nn < 2; ++nn) {
      b01[0][nn] = *(const bf16x8*)(Bp + boffb + nn * 1024 + ch0);
      b01[1][nn] = *(const bf16x8*)(Bp + boffb + nn * 1024 + ch1);
    }
    if (t + 1 < nt) STG_A(t + 1, 0);
    __builtin_amdgcn_s_barrier();
    asm volatile("s_waitcnt lgkmcnt(0)" ::: "memory");
    __builtin_amdgcn_s_setprio(1);
#pragma unroll
    for (int kk = 0; kk < 2; ++kk)
#pragma unroll
      for (int mm = 0; mm < 4; ++mm)
#pragma unroll
        for (int nn = 0; nn < 2; ++nn)
          acc[mm][nn] = __builtin_amdgcn_mfma_f32_16x16x32_bf16(a[kk][mm], b01[kk][nn], acc[mm][nn], 0, 0, 0);
    __builtin_amdgcn_s_setprio(0);
    __builtin_amdgcn_s_barrier();

    // ---- p2: quadrant (mh0, n23)
#pragma unroll
    for (int nn = 0; nn < 2; ++nn) {
      b23[0][nn] = *(const bf16x8*)(Bp + boffb + (2 + nn) * 1024 + ch0);
      b23[1][nn] = *(const bf16x8*)(Bp + boffb + (2 + nn) * 1024 + ch1);
    }
    if (t + 1 < nt) STG_A(t + 1, 1);
    __builtin_amdgcn_s_barrier();
    asm volatile("s_waitcnt lgkmcnt(0)" ::: "memory");
    __builtin_amdgcn_s_setprio(1);
#pragma unroll
    for (int kk = 0; kk < 2; ++kk)
#pragma unroll
      for (int mm = 0; mm < 4; ++mm)
#pragma unroll
        for (int nn = 0; nn < 2; ++nn)
          acc[mm][2 + nn] = __builtin_amdgcn_mfma_f32_16x16x32_bf16(a[kk][mm], b23[kk][nn], acc[mm][2 + nn], 0, 0, 0);
    __builtin_amdgcn_s_setprio(0);
    __builtin_amdgcn_s_barrier();

    // ---- p3: quadrant (mh1, n23); B(t) fully consumed at p2 -> stage B-lo(t+2) into this buf
#pragma unroll
    for (int mm = 0; mm < 4; ++mm) {
      a[0][mm] = *(const bf16x8*)(Ap + aoffb + (4 + mm) * 1024 + ch0);
      a[1][mm] = *(const bf16x8*)(Ap + aoffb + (4 + mm) * 1024 + ch1);
    }
    if (t + 2 < nt) STG_B(t + 2, 0);
    __builtin_amdgcn_s_barrier();
    asm volatile("s_waitcnt lgkmcnt(0)" ::: "memory");
    __builtin_amdgcn_s_setprio(1);
#pragma unroll
    for (int kk = 0; kk < 2; ++kk)
#pragma unroll
      for (int mm = 0; mm < 4; ++mm)
#pragma unroll
        for (int nn = 0; nn < 2; ++nn)
          acc[4 + mm][2 + nn] = __builtin_amdgcn_mfma_f32_16x16x32_bf16(a[kk][mm], b23[kk][nn], acc[4 + mm][2 + nn], 0, 0, 0);
    __builtin_amdgcn_s_setprio(0);
    __builtin_amdgcn_s_barrier();

    // ---- p4: quadrant (mh1, n01)
    if (t + 2 < nt) STG_B(t + 2, 1);
    __builtin_amdgcn_s_barrier();
    __builtin_amdgcn_s_setprio(1);
#pragma unroll
    for (int kk = 0; kk < 2; ++kk)
#pragma unroll
      for (int mm = 0; mm < 4; ++mm)
#pragma unroll
        for (int nn = 0; nn < 2; ++nn)
          acc[4 + mm][nn] = __builtin_amdgcn_mfma_f32_16x16x32_bf16(a[kk][mm], b01[kk][nn], acc[4 + mm][nn], 0, 0, 0);
    __builtin_amdgcn_s_setprio(0);
    // boundary: A(t+1) [issued p1/p2] must land; B(t+2) [p3/p4] may stay in flight
    if (t + 1 < nt) {
      if (t + 2 < nt) asm volatile("s_waitcnt vmcnt(4)" ::: "memory");
      else            asm volatile("s_waitcnt vmcnt(0)" ::: "memory");
    }
    __builtin_amdgcn_s_barrier();
  }
#undef STG_A
#undef STG_B

  const int rbase = bm * 256 + wm * 128;
  const int cbase = bn * 256 + wn * 64;
#pragma unroll
  for (int m = 0; m < 8; ++m) {
#pragma unroll
    for (int n = 0; n < 4; ++n) {
      const int col = cbase + n * 16 + l15;
      const int row0 = rbase + m * 16 + e4 * 4;
      const float bv = bias[col];
#pragma unroll
      for (int r = 0; r < 4; ++r) {
        const int row = row0 + r;
        float v = acc[m][n][r] + bv;
        if (EPI == 2) {
          float tt = v * (1.0f + 0.044715f * v * v);
          float sg = 1.0f / (1.0f + __expf(-1.5957691216057308f * tt));
          ((u16*)outp)[(size_t)row * N + col] = f2bf(v * sg);
        } else {
          ((u16*)outp)[(size_t)row * N + col] = f2bf(v);
        }
      }
    }
  }
}

// ---------------- GEMM: 128-row tile (O-proj, MLP2) ----------------
template <int EPI, int BN>
__global__ __launch_bounds__(256, (BN == 64) ? 3 : 2)
void gemm_bt(const u16* __restrict__ A, const u16* __restrict__ BT,
             const float* __restrict__ bias, const float* __restrict__ res,
             void* __restrict__ outp, int M, int N, int K) {
  constexpr int MF = (BN == 128) ? 4 : 2;
  constexpr int ACH = 4;
  constexpr int BCH = BN / 32;
  constexpr int LOADS = ACH + BCH;
  __shared__ __align__(16) u16 As[2][128 * 64];
  __shared__ __align__(16) u16 Bs[2][BN * 64];
  const int nBN = N / BN;
  const int hw = blockIdx.x;
  const int xcd = hw & 7;
  const int rr = hw >> 3;
  const int bm = xcd * 4 + rr / nBN;
  const int bn = rr % nBN;
  const int tid = threadIdx.x;
  const int lane = tid & 63;
  const int wid = tid >> 6;
  const int wm = (BN == 128) ? (wid >> 1) : wid;
  const int wn = (BN == 128) ? (wid & 1) : 0;
  const int e4 = lane >> 4;

  int abase[MF], ax[MF];
#pragma unroll
  for (int m = 0; m < MF; ++m) {
    int rowa = wm * (MF * 16) + m * 16 + (lane & 15);
    abase[m] = rowa * 64; ax[m] = rowa & 7;
  }
  int bbase[4], bx[4];
#pragma unroll
  for (int n = 0; n < 4; ++n) {
    int rowb = wn * 64 + n * 16 + (lane & 15);
    bbase[n] = rowb * 64; bx[n] = rowb & 7;
  }

  size_t ga[ACH]; int loa[ACH];
#pragma unroll
  for (int c = 0; c < ACH; ++c) {
    int idx = tid + (c << 8);
    int row = idx >> 3;
    int ch = (idx & 7) ^ (row & 7);
    ga[c] = (size_t)(bm * 128 + row) * K + (ch << 3);
    loa[c] = idx << 4;
  }
  size_t gb[BCH]; int lob[BCH];
#pragma unroll
  for (int c = 0; c < BCH; ++c) {
    int idx = tid + (c << 8);
    int row = idx >> 3;
    int ch = (idx & 7) ^ (row & 7);
    gb[c] = (size_t)(bn * BN + row) * K + (ch << 3);
    lob[c] = idx << 4;
  }

#define STAGE_G(t, bb) do { \
  _Pragma("unroll") for (int c = 0; c < ACH; ++c) \
    GLOAD16(A + ga[c] + (size_t)(t) * 64, (char*)As[bb] + loa[c]); \
  _Pragma("unroll") for (int c = 0; c < BCH; ++c) \
    GLOAD16(BT + gb[c] + (size_t)(t) * 64, (char*)Bs[bb] + lob[c]); \
} while (0)

  f32x4 acc[MF][4] = {};
  const int nt = K >> 6;

  STAGE_G(0, 0);
  STAGE_G(1, 1);

  for (int t = 0; t < nt; ++t) {
    if (t + 1 < nt) {
      asm volatile("s_waitcnt vmcnt(%0)" :: "i"(LOADS) : "memory");
    } else {
      asm volatile("s_waitcnt vmcnt(0)" ::: "memory");
    }
    __builtin_amdgcn_s_barrier();
    const u16* Ap = As[t & 1];
    const u16* Bp = Bs[t & 1];
    bf16x8 af[2][MF], bfr[2][4];
#pragma unroll
    for (int kk = 0; kk < 2; ++kk) {
#pragma unroll
      for (int m = 0; m < MF; ++m)
        af[kk][m] = *(const bf16x8*)(Ap + abase[m] + (((((kk << 2) | e4)) ^ ax[m]) << 3));
#pragma unroll
      for (int n = 0; n < 4; ++n)
        bfr[kk][n] = *(const bf16x8*)(Bp + bbase[n] + (((((kk << 2) | e4)) ^ bx[n]) << 3));
    }
    asm volatile("s_waitcnt lgkmcnt(0)" ::: "memory");
    __builtin_amdgcn_s_barrier();
    if (t + 2 < nt) STAGE_G(t + 2, t & 1);
    __builtin_amdgcn_s_setprio(1);
#pragma unroll
    for (int kk = 0; kk < 2; ++kk)
#pragma unroll
      for (int m = 0; m < MF; ++m)
#pragma unroll
        for (int n = 0; n < 4; ++n)
          acc[m][n] = __builtin_amdgcn_mfma_f32_16x16x32_bf16(af[kk][m], bfr[kk][n], acc[m][n], 0, 0, 0);
    __builtin_amdgcn_s_setprio(0);
  }
#undef STAGE_G

  const int rbase = bm * 128 + wm * (MF * 16);
  const int cbase = bn * BN + wn * 64;
#pragma unroll
  for (int m = 0; m < MF; ++m) {
#pragma unroll
    for (int n = 0; n < 4; ++n) {
      const int col = cbase + n * 16 + (lane & 15);
      const int row0 = rbase + m * 16 + ((lane >> 4) << 2);
      const float bv = bias[col];
#pragma unroll
      for (int r = 0; r < 4; ++r) {
        const int row = row0 + r;
        float v = acc[m][n][r] + bv;
        if (EPI == 1) {
          ((float*)outp)[(size_t)row * N + col] = v + res[(size_t)row * N + col];
        } else if (EPI == 2) {
          float tt = v * (1.0f + 0.044715f * v * v);
          float sg = 1.0f / (1.0f + __expf(-1.5957691216057308f * tt));
          ((u16*)outp)[(size_t)row * N + col] = f2bf(v * sg);
        } else {
          ((u16*)outp)[(size_t)row * N + col] = f2bf(v);
        }
      }
    }
  }
}

// ---------------- causal flash attention, 8-warp 32x32 swapped (R8 best: 60.6us) ----------------
__global__ __launch_bounds__(512, 2) void attn_kernel(const u16* __restrict__ QKV,
                                                      u16* __restrict__ O) {
  __shared__ __align__(16) u16 KV[4][4096];  // K0,K1,V0,V1; epilogue reuse
  const int T = 2048, LD = 3072;
  const int blk = blockIdx.x;
  const int xcd = blk & 7;
  const int i = blk >> 3;
  const int bh = xcd * 4 + (i & 3);
  const int p = i >> 2;
  const int b = bh >> 4, hd = bh & 15;
  const int tid = threadIdx.x;
  const int lane = tid & 63;
  const int w = tid >> 6;
  const int h = lane >> 5;
  const int cA = p, cB = 15 - p;
  const int myc = (w < 4) ? cA : cB;
  const int qwb = myc * 128 + (w & 3) * 32;
  const int qg = qwb + (lane & 31);
  const int diag = qwb >> 6;
  const int myNt = diag + 1;
  const int nt = 2 * cB + 2;

  const u16* Qb = QKV + (size_t)b * T * LD + hd * 64;
  const u16* Kb = Qb + 1024;
  const u16* Vb = Qb + 2048;

  const float QSC = 0.18033688011112042f;
  bf16x8 qf[4];
#pragma unroll
  for (int s = 0; s < 4; ++s) {
    bf16x8 raw = *(const bf16x8*)(Qb + (size_t)qg * LD + s * 16 + h * 8);
    union { unsigned wd[4]; bf16x8 v; } u;
#pragma unroll
    for (int e = 0; e < 4; ++e)
      u.wd[e] = cvtpk(bf2f((u16)raw[2 * e]) * QSC, bf2f((u16)raw[2 * e + 1]) * QSC);
    qf[s] = u.v;
  }

  f32x16 oacc[2] = {};
  float m = -INFINITY, l = 0.0f;

  const int srow = tid >> 3;
  const int scol = tid & 7;
  const int kgc = ((scol ^ (srow & 7)) << 3);

  GLOAD16(Kb + (size_t)srow * LD + kgc, (char*)KV[0] + tid * 16);
  {
    bf16x8 vv0 = *(const bf16x8*)(Vb + (size_t)srow * LD + scol * 8);
#pragma unroll
    for (int e = 0; e < 8; ++e) {
      int d = scol * 8 + e;
      KV[2][(d << 6) | (srow & 7) | ((((srow >> 3) ^ e ^ scol) & 7) << 3)] = (u16)vv0[e];
    }
  }
  __syncthreads();

  int cur = 0;
  for (int j = 0; j < nt; ++j) {
    const bool pre = (j + 1 < nt);
    bf16x8 vv;
    if (pre) {
      GLOAD16(Kb + (size_t)((j + 1) * 64 + srow) * LD + kgc, (char*)KV[cur ^ 1] + tid * 16);
      vv = *(const bf16x8*)(Vb + (size_t)((j + 1) * 64 + srow) * LD + scol * 8);
    }

    if (j < myNt) {
      f32x16 sacc[2] = {};
      const u16* Kp = KV[cur];
      __builtin_amdgcn_s_setprio(1);
#pragma unroll
      for (int t = 0; t < 2; ++t) {
#pragma unroll
        for (int s = 0; s < 4; ++s) {
          int row = t * 32 + (lane & 31);
          bf16x8 kf = *(const bf16x8*)(Kp + (row << 6) + ((((2 * s + h) ^ (row & 7)) & 7) << 3));
          sacc[t] = __builtin_amdgcn_mfma_f32_32x32x16_bf16(kf, qf[s], sacc[t], 0, 0, 0);
        }
      }
      __builtin_amdgcn_s_setprio(0);

      if (j == diag) {
#pragma unroll
        for (int t = 0; t < 2; ++t)
#pragma unroll
          for (int r = 0; r < 16; ++r) {
            int key = (j << 6) + 32 * t + (r & 3) + 8 * (r >> 2) + 4 * h;
            if (key > qg) sacc[t][r] = -INFINITY;
          }
      }

      float pmax = -INFINITY;
#pragma unroll
      for (int t = 0; t < 2; ++t)
#pragma unroll
        for (int r = 0; r < 16; ++r) pmax = fmaxf(pmax, sacc[t][r]);
      pmax = fmaxf(pmax, __shfl_xor(pmax, 32, 64));

      if (!__all(pmax - m <= 2.8853900817779268f)) {
        float mn = fmaxf(m, pmax);
        float alpha = exp2f(m - mn);
        m = mn;
        l *= alpha;
#pragma unroll
        for (int d2 = 0; d2 < 2; ++d2)
#pragma unroll
          for (int r = 0; r < 16; ++r) oacc[d2][r] *= alpha;
      }

      float lsum = 0.0f;
#pragma unroll
      for (int t = 0; t < 2; ++t)
#pragma unroll
        for (int r = 0; r < 16; ++r) {
          float pe = exp2f(sacc[t][r] - m);
          sacc[t][r] = pe;
          lsum += pe;
        }
      lsum += __shfl_xor(lsum, 32, 64);
      l += lsum;

      union PF { unsigned wd[4]; bf16x8 v; } pf[4];
#pragma unroll
      for (int t = 0; t < 2; ++t) {
#pragma unroll
        for (int kb = 0; kb < 2; ++kb) {
          int base = 8 * kb;
          unsigned A0 = cvtpk(sacc[t][base + 0], sacc[t][base + 1]);
          unsigned A2 = cvtpk(sacc[t][base + 2], sacc[t][base + 3]);
          unsigned A4 = cvtpk(sacc[t][base + 4], sacc[t][base + 5]);
          unsigned A6 = cvtpk(sacc[t][base + 6], sacc[t][base + 7]);
          unsigned S0 = (unsigned)__shfl_xor((int)(h ? A0 : A4), 32, 64);
          unsigned S2 = (unsigned)__shfl_xor((int)(h ? A2 : A6), 32, 64);
          PF& u = pf[2 * t + kb];
          u.wd[0] = h ? S0 : A0;
          u.wd[1] = h ? S2 : A2;
          u.wd[2] = h ? A4 : S0;
          u.wd[3] = h ? A6 : S2;
        }
      }

      const u16* Vp = KV[2 + cur];
      __builtin_amdgcn_s_setprio(1);
#pragma unroll
      for (int d2 = 0; d2 < 2; ++d2) {
        int d = d2 * 32 + (lane & 31);
#pragma unroll
        for (int ks = 0; ks < 4; ++ks) {
          bf16x8 vf = *(const bf16x8*)(Vp + (d << 6) + ((((2 * ks + h) ^ (d & 7) ^ ((d >> 3) & 7)) & 7) << 3));
          oacc[d2] = __builtin_amdgcn_mfma_f32_32x32x16_bf16(vf, pf[ks].v, oacc[d2], 0, 0, 0);
        }
      }
      __builtin_amdgcn_s_setprio(0);
    }

    if (pre) {
#pragma unroll
      for (int e = 0; e < 8; ++e) {
        int d = scol * 8 + e;
        KV[2 + (cur ^ 1)][(d << 6) | (srow & 7) | ((((srow >> 3) ^ e ^ scol) & 7) << 3)] = (u16)vv[e];
      }
    }
    __syncthreads();
    cur ^= 1;
  }

  const float rinv = 1.0f / l;
  u16* Ob = (u16*)KV;
  const int qloc = w * 32 + (lane & 31);
#pragma unroll
  for (int d2 = 0; d2 < 2; ++d2)
#pragma unroll
    for (int r = 0; r < 16; ++r) {
      int d = d2 * 32 + (r & 3) + 8 * (r >> 2) + 4 * h;
      Ob[(qloc << 6) | (d ^ ((qloc & 7) << 3))] = f2bf(oacc[d2][r] * rinv);
    }
  __syncthreads();
#pragma unroll
  for (int it = 0; it < 4; ++it) {
    int r = (tid >> 3) + it * 64;
    int c = tid & 7;
    bf16x8 val = *(const bf16x8*)(Ob + (r << 6) + (((c ^ (r & 7)) & 7) << 3));
    int qg2 = (r < 128) ? (cA * 128 + r) : (cB * 128 + (r - 128));
    *(bf16x8*)(O + (size_t)(b * T + qg2) * 1024 + hd * 64 + c * 8) = val;
  }
}

// ---------------- host launch ----------------
extern "C" void kernel_launch(void* const* d_in, const int* in_sizes, int n_in,
                              void* d_out, int out_size, void* d_ws, size_t ws_size,
                              hipStream_t stream) {
  const float* x      = (const float*)d_in[0];
  const float* gamma1 = (const float*)d_in[1];
  const float* beta1  = (const float*)d_in[2];
  const float* Wq     = (const float*)d_in[3];
  const float* bq     = (const float*)d_in[4];
  const float* Wk     = (const float*)d_in[5];
  const float* bk     = (const float*)d_in[6];
  const float* Wv     = (const float*)d_in[7];
  const float* bv     = (const float*)d_in[8];
  const float* Wo     = (const float*)d_in[9];
  const float* bo     = (const float*)d_in[10];
  const float* gamma2 = (const float*)d_in[11];
  const float* beta2  = (const float*)d_in[12];
  const float* W1     = (const float*)d_in[13];
  const float* b1     = (const float*)d_in[14];
  const float* W2     = (const float*)d_in[15];
  const float* b2     = (const float*)d_in[16];

  char* ws = (char*)d_ws;  // 64 MB layout
  u16* WqkvT = (u16*)(ws + 0 * MB);
  u16* WoT   = (u16*)(ws + 6 * MB);
  u16* W1T   = (u16*)(ws + 8 * MB);
  u16* W2T   = (u16*)(ws + 16 * MB);
  u16* qkv   = (u16*)(ws + 24 * MB);
  u16* hb    = (u16*)(ws + 24 * MB);
  u16* xn    = (u16*)(ws + 56 * MB);
  float* bqkv = (float*)d_out;
  float* x1 = (float*)d_out;

  const int M = 4096;

  wprep<<<dim3(16388), dim3(256), 0, stream>>>(Wq, Wk, Wv, Wo, W1, W2, bq, bk, bv,
                                               WqkvT, WoT, W1T, W2T, bqkv,
                                               x, gamma1, beta1, xn);

  // QKV: 256x256 8-phase schedule (192 blocks)
  gemm256sq<0><<<dim3(192), dim3(512), 0, stream>>>(xn, WqkvT, bqkv, qkv, M, 3072, 1024);

  attn_kernel<<<dim3(256), dim3(512), 0, stream>>>(qkv, xn);

  gemm_bt<1, 64><<<dim3(512), dim3(256), 0, stream>>>(xn, WoT, bo, x, x1, M, 1024, 1024);

  ln_kernel<<<dim3(M), dim3(256), 0, stream>>>(x1, gamma2, beta2, xn);

  // MLP1: 256x256 8-phase schedule (256 blocks), GELU epilogue
  gemm256sq<2><<<dim3(256), dim3(512), 0, stream>>>(xn, W1T, b1, hb, M, 4096, 1024);
  gemm_bt<1, 64><<<dim3(512), dim3(256), 0, stream>>>(hb, W2T, b2, x1, d_out, M, 1024, 4096);
}

// Round 14
// 215.329 us; speedup vs baseline: 1.1200x; 1.0205x over previous
//
#include <hip/hip_runtime.h>
#include <stdint.h>

typedef unsigned short u16;
typedef short bf16x8 __attribute__((ext_vector_type(8)));
typedef float f32x4 __attribute__((ext_vector_type(4)));
typedef float f32x16 __attribute__((ext_vector_type(16)));

#define MB (1024L*1024L)

__device__ inline u16 f2bf(float f) {
  union { float f; unsigned u; } v; v.f = f;
  unsigned r = (v.u + 0x7FFFu + ((v.u >> 16) & 1u)) >> 16;
  return (u16)r;
}

__device__ inline float bf2f(u16 u) {
  union { unsigned u; float f; } v; v.u = ((unsigned)u) << 16; return v.f;
}

__device__ inline unsigned cvtpk(float lo, float hi) {
  unsigned r;
  asm("v_cvt_pk_bf16_f32 %0, %1, %2" : "=v"(r) : "v"(lo), "v"(hi));
  return r;
}

#define GLOAD16(gptr, lptr) \
  __builtin_amdgcn_global_load_lds((__attribute__((address_space(1))) void*)(gptr), \
                                   (__attribute__((address_space(3))) void*)(lptr), 16, 0, 0)

// ------- merged prep: 6 weight transposes + bias concat + LN1 -------
__global__ __launch_bounds__(256) void wprep(
    const float* __restrict__ Wq, const float* __restrict__ Wk,
    const float* __restrict__ Wv, const float* __restrict__ Wo,
    const float* __restrict__ W1, const float* __restrict__ W2,
    const float* __restrict__ bq, const float* __restrict__ bk,
    const float* __restrict__ bv,
    u16* __restrict__ WqkvT, u16* __restrict__ WoT,
    u16* __restrict__ W1T, u16* __restrict__ W2T, float* __restrict__ bqkv,
    const float* __restrict__ x, const float* __restrict__ gamma1,
    const float* __restrict__ beta1, u16* __restrict__ xn) {
  const int blk = blockIdx.x;
  const int tid = threadIdx.x;
  __shared__ float tile[32][33];
  __shared__ float red[8];

  if (blk >= 12292) {  // LN1 rows (4096 blocks)
    const int row = blk - 12292;
    const float4 v = *(const float4*)(x + (size_t)row * 1024 + tid * 4);
    float s = v.x + v.y + v.z + v.w;
    float s2 = v.x * v.x + v.y * v.y + v.z * v.z + v.w * v.w;
#pragma unroll
    for (int mm = 1; mm < 64; mm <<= 1) {
      s += __shfl_xor(s, mm, 64);
      s2 += __shfl_xor(s2, mm, 64);
    }
    const int w = tid >> 6;
    if ((tid & 63) == 0) { red[w] = s; red[4 + w] = s2; }
    __syncthreads();
    s = red[0] + red[1] + red[2] + red[3];
    s2 = red[4] + red[5] + red[6] + red[7];
    const float mean = s * (1.0f / 1024.0f);
    const float var = s2 * (1.0f / 1024.0f) - mean * mean;
    const float rstd = rsqrtf(var + 1e-5f);
    const float4 g = *(const float4*)(gamma1 + tid * 4);
    const float4 bb = *(const float4*)(beta1 + tid * 4);
    ushort4 o;
    o.x = f2bf(g.x * (v.x - mean) * rstd + bb.x);
    o.y = f2bf(g.y * (v.y - mean) * rstd + bb.y);
    o.z = f2bf(g.z * (v.z - mean) * rstd + bb.z);
    o.w = f2bf(g.w * (v.w - mean) * rstd + bb.w);
    *(ushort4*)(xn + (size_t)row * 1024 + tid * 4) = o;
    return;
  }
  if (blk >= 12288) {  // bias concat
    int i = (blk - 12288) * 256 + tid;
    bqkv[i] = bq[i]; bqkv[1024 + i] = bk[i]; bqkv[2048 + i] = bv[i];
    return;
  }
  const float* W; u16* WT; int K, N, tb;
  if (blk < 4096) {
    K = 1024; N = 1024;
    if (blk < 1024)      { W = Wq; WT = WqkvT;               tb = blk; }
    else if (blk < 2048) { W = Wk; WT = WqkvT + 1024 * 1024; tb = blk - 1024; }
    else if (blk < 3072) { W = Wv; WT = WqkvT + 2048 * 1024; tb = blk - 2048; }
    else                 { W = Wo; WT = WoT;                 tb = blk - 3072; }
  } else if (blk < 8192) { W = W1; WT = W1T; K = 1024; N = 4096; tb = blk - 4096; }
  else                   { W = W2; WT = W2T; K = 4096; N = 1024; tb = blk - 8192; }

  const int nbn = N >> 5;
  const int bk_ = tb / nbn;
  const int bn = tb % nbn;
  const int r = tid >> 3;
  const int c4 = (tid & 7) << 2;
  const float4 v = *(const float4*)(W + (size_t)(bk_ * 32 + r) * N + bn * 32 + c4);
  tile[r][c4 + 0] = v.x; tile[r][c4 + 1] = v.y;
  tile[r][c4 + 2] = v.z; tile[r][c4 + 3] = v.w;
  __syncthreads();
  ushort4 o;
  o.x = f2bf(tile[c4 + 0][r]); o.y = f2bf(tile[c4 + 1][r]);
  o.z = f2bf(tile[c4 + 2][r]); o.w = f2bf(tile[c4 + 3][r]);
  *(ushort4*)(WT + (size_t)(bn * 32 + r) * K + bk_ * 32 + c4) = o;
}

// ---------------- LayerNorm fp32 -> bf16 (LN2) ----------------
__global__ __launch_bounds__(256) void ln_kernel(const float* __restrict__ x,
                                                 const float* __restrict__ gamma,
                                                 const float* __restrict__ beta,
                                                 u16* __restrict__ out) {
  const int row = blockIdx.x;
  const int tid = threadIdx.x;
  const float4 v = *(const float4*)(x + (size_t)row * 1024 + tid * 4);
  float s = v.x + v.y + v.z + v.w;
  float s2 = v.x * v.x + v.y * v.y + v.z * v.z + v.w * v.w;
#pragma unroll
  for (int m = 1; m < 64; m <<= 1) {
    s += __shfl_xor(s, m, 64);
    s2 += __shfl_xor(s2, m, 64);
  }
  __shared__ float red[8];
  const int w = tid >> 6;
  if ((tid & 63) == 0) { red[w] = s; red[4 + w] = s2; }
  __syncthreads();
  s = red[0] + red[1] + red[2] + red[3];
  s2 = red[4] + red[5] + red[6] + red[7];
  const float mean = s * (1.0f / 1024.0f);
  const float var = s2 * (1.0f / 1024.0f) - mean * mean;
  const float rstd = rsqrtf(var + 1e-5f);
  const float4 g = *(const float4*)(gamma + tid * 4);
  const float4 b = *(const float4*)(beta + tid * 4);
  ushort4 o;
  o.x = f2bf(g.x * (v.x - mean) * rstd + b.x);
  o.y = f2bf(g.y * (v.y - mean) * rstd + b.y);
  o.z = f2bf(g.z * (v.z - mean) * rstd + b.z);
  o.w = f2bf(g.w * (v.w - mean) * rstd + b.w);
  *(ushort4*)(out + (size_t)row * 1024 + tid * 4) = o;
}

// ---- GEMM 256x256, 8 waves, 4 quadrant-phases/K-tile, counted vmcnt(4), dbuf ----
template <int EPI>
__global__ __launch_bounds__(512, 1)
void gemm256sq(const u16* __restrict__ A, const u16* __restrict__ BT,
               const float* __restrict__ bias, void* __restrict__ outp,
               int M, int N, int K) {
  __shared__ __align__(16) u16 As[2][256 * 64];
  __shared__ __align__(16) u16 Bs[2][256 * 64];
  const int nBN = N >> 8;
  const int blk = blockIdx.x;
  const int xcd = blk & 7;
  const int rr = blk >> 3;
  const int bm = xcd * 2 + rr / nBN;
  const int bn = rr % nBN;
  const int tid = threadIdx.x;
  const int lane = tid & 63;
  const int wid = tid >> 6;
  const int wm = wid >> 2;
  const int wn = wid & 3;
  const int e4 = lane >> 4;
  const int l15 = lane & 15;
  const int sx = l15 & 7;

  const int aoffb = (wm * 128 + l15) * 64;
  const int boffb = (wn * 64 + l15) * 64;
  const int ch0 = ((e4 ^ sx) & 7) << 3;
  const int ch1 = (((4 | e4) ^ sx) & 7) << 3;

  size_t gA[2], gB[2]; int lo[2];
#pragma unroll
  for (int c = 0; c < 2; ++c) {
    int idx = tid + (c << 9);
    int rowl = idx >> 3;
    int chg = ((idx & 7) ^ (rowl & 7)) << 3;
    gA[c] = (size_t)(bm * 256 + rowl) * K + chg;
    gB[c] = (size_t)(bn * 256 + rowl) * K + chg;
    lo[c] = idx << 4;
  }
  const size_t hK = (size_t)128 * K;

#define STG_A(tt, h) do { _Pragma("unroll") for (int c = 0; c < 2; ++c) \
  GLOAD16(A + gA[c] + (size_t)(h) * hK + (size_t)(tt) * 64, (char*)As[(tt) & 1] + (h) * 16384 + lo[c]); } while (0)
#define STG_B(tt, h) do { _Pragma("unroll") for (int c = 0; c < 2; ++c) \
  GLOAD16(BT + gB[c] + (size_t)(h) * hK + (size_t)(tt) * 64, (char*)Bs[(tt) & 1] + (h) * 16384 + lo[c]); } while (0)

  f32x4 acc[8][4] = {};
  const int nt = K >> 6;

  STG_A(0, 0); STG_A(0, 1); STG_B(0, 0); STG_B(0, 1);
  STG_B(1, 0); STG_B(1, 1);
  asm volatile("s_waitcnt vmcnt(4)" ::: "memory");
  __builtin_amdgcn_s_barrier();

  for (int t = 0; t < nt; ++t) {
    const u16* Ap = As[t & 1];
    const u16* Bp = Bs[t & 1];
    bf16x8 a[2][4], b01[2][2], b23[2][2];

    // p1: (mh0, n01)
#pragma unroll
    for (int mm = 0; mm < 4; ++mm) {
      a[0][mm] = *(const bf16x8*)(Ap + aoffb + mm * 1024 + ch0);
      a[1][mm] = *(const bf16x8*)(Ap + aoffb + mm * 1024 + ch1);
    }
#pragma unroll
    for (int nn = 0; nn < 2; ++nn) {
      b01[0][nn] = *(const bf16x8*)(Bp + boffb + nn * 1024 + ch0);
      b01[1][nn] = *(const bf16x8*)(Bp + boffb + nn * 1024 + ch1);
    }
    if (t + 1 < nt) STG_A(t + 1, 0);
    __builtin_amdgcn_s_barrier();
    asm volatile("s_waitcnt lgkmcnt(0)" ::: "memory");
    __builtin_amdgcn_s_setprio(1);
#pragma unroll
    for (int kk = 0; kk < 2; ++kk)
#pragma unroll
      for (int mm = 0; mm < 4; ++mm)
#pragma unroll
        for (int nn = 0; nn < 2; ++nn)
          acc[mm][nn] = __builtin_amdgcn_mfma_f32_16x16x32_bf16(a[kk][mm], b01[kk][nn], acc[mm][nn], 0, 0, 0);
    __builtin_amdgcn_s_setprio(0);
    __builtin_amdgcn_s_barrier();

    // p2: (mh0, n23)
#pragma unroll
    for (int nn = 0; nn < 2; ++nn) {
      b23[0][nn] = *(const bf16x8*)(Bp + boffb + (2 + nn) * 1024 + ch0);
      b23[1][nn] = *(const bf16x8*)(Bp + boffb + (2 + nn) * 1024 + ch1);
    }
    if (t + 1 < nt) STG_A(t + 1, 1);
    __builtin_amdgcn_s_barrier();
    asm volatile("s_waitcnt lgkmcnt(0)" ::: "memory");
    __builtin_amdgcn_s_setprio(1);
#pragma unroll
    for (int kk = 0; kk < 2; ++kk)
#pragma unroll
      for (int mm = 0; mm < 4; ++mm)
#pragma unroll
        for (int nn = 0; nn < 2; ++nn)
          acc[mm][2 + nn] = __builtin_amdgcn_mfma_f32_16x16x32_bf16(a[kk][mm], b23[kk][nn], acc[mm][2 + nn], 0, 0, 0);
    __builtin_amdgcn_s_setprio(0);
    __builtin_amdgcn_s_barrier();

    // p3: (mh1, n23)
#pragma unroll
    for (int mm = 0; mm < 4; ++mm) {
      a[0][mm] = *(const bf16x8*)(Ap + aoffb + (4 + mm) * 1024 + ch0);
      a[1][mm] = *(const bf16x8*)(Ap + aoffb + (4 + mm) * 1024 + ch1);
    }
    if (t + 2 < nt) STG_B(t + 2, 0);
    __builtin_amdgcn_s_barrier();
    asm volatile("s_waitcnt lgkmcnt(0)" ::: "memory");
    __builtin_amdgcn_s_setprio(1);
#pragma unroll
    for (int kk = 0; kk < 2; ++kk)
#pragma unroll
      for (int mm = 0; mm < 4; ++mm)
#pragma unroll
        for (int nn = 0; nn < 2; ++nn)
          acc[4 + mm][2 + nn] = __builtin_amdgcn_mfma_f32_16x16x32_bf16(a[kk][mm], b23[kk][nn], acc[4 + mm][2 + nn], 0, 0, 0);
    __builtin_amdgcn_s_setprio(0);
    __builtin_amdgcn_s_barrier();

    // p4: (mh1, n01)
    if (t + 2 < nt) STG_B(t + 2, 1);
    __builtin_amdgcn_s_barrier();
    __builtin_amdgcn_s_setprio(1);
#pragma unroll
    for (int kk = 0; kk < 2; ++kk)
#pragma unroll
      for (int mm = 0; mm < 4; ++mm)
#pragma unroll
        for (int nn = 0; nn < 2; ++nn)
          acc[4 + mm][nn] = __builtin_amdgcn_mfma_f32_16x16x32_bf16(a[kk][mm], b01[kk][nn], acc[4 + mm][nn], 0, 0, 0);
    __builtin_amdgcn_s_setprio(0);
    if (t + 1 < nt) {
      if (t + 2 < nt) asm volatile("s_waitcnt vmcnt(4)" ::: "memory");
      else            asm volatile("s_waitcnt vmcnt(0)" ::: "memory");
    }
    __builtin_amdgcn_s_barrier();
  }
#undef STG_A
#undef STG_B

  const int rbase = bm * 256 + wm * 128;
  const int cbase = bn * 256 + wn * 64;
#pragma unroll
  for (int m = 0; m < 8; ++m) {
#pragma unroll
    for (int n = 0; n < 4; ++n) {
      const int col = cbase + n * 16 + l15;
      const int row0 = rbase + m * 16 + e4 * 4;
      const float bv = bias[col];
#pragma unroll
      for (int r = 0; r < 4; ++r) {
        const int row = row0 + r;
        float v = acc[m][n][r] + bv;
        if (EPI == 2) {
          float tt = v * (1.0f + 0.044715f * v * v);
          float sg = 1.0f / (1.0f + __expf(-1.5957691216057308f * tt));
          ((u16*)outp)[(size_t)row * N + col] = f2bf(v * sg);
        } else {
          ((u16*)outp)[(size_t)row * N + col] = f2bf(v);
        }
      }
    }
  }
}

// ---------------- GEMM: 128-row tile (O-proj, MLP2) ----------------
template <int EPI, int BN>
__global__ __launch_bounds__(256, (BN == 64) ? 3 : 2)
void gemm_bt(const u16* __restrict__ A, const u16* __restrict__ BT,
             const float* __restrict__ bias, const float* __restrict__ res,
             void* __restrict__ outp, int M, int N, int K) {
  constexpr int MF = (BN == 128) ? 4 : 2;
  constexpr int ACH = 4;
  constexpr int BCH = BN / 32;
  constexpr int LOADS = ACH + BCH;
  __shared__ __align__(16) u16 As[2][128 * 64];
  __shared__ __align__(16) u16 Bs[2][BN * 64];
  const int nBN = N / BN;
  const int hw = blockIdx.x;
  const int xcd = hw & 7;
  const int rr = hw >> 3;
  const int bm = xcd * 4 + rr / nBN;
  const int bn = rr % nBN;
  const int tid = threadIdx.x;
  const int lane = tid & 63;
  const int wid = tid >> 6;
  const int wm = (BN == 128) ? (wid >> 1) : wid;
  const int wn = (BN == 128) ? (wid & 1) : 0;
  const int e4 = lane >> 4;

  int abase[MF], ax[MF];
#pragma unroll
  for (int m = 0; m < MF; ++m) {
    int rowa = wm * (MF * 16) + m * 16 + (lane & 15);
    abase[m] = rowa * 64; ax[m] = rowa & 7;
  }
  int bbase[4], bx[4];
#pragma unroll
  for (int n = 0; n < 4; ++n) {
    int rowb = wn * 64 + n * 16 + (lane & 15);
    bbase[n] = rowb * 64; bx[n] = rowb & 7;
  }

  size_t ga[ACH]; int loa[ACH];
#pragma unroll
  for (int c = 0; c < ACH; ++c) {
    int idx = tid + (c << 8);
    int row = idx >> 3;
    int ch = (idx & 7) ^ (row & 7);
    ga[c] = (size_t)(bm * 128 + row) * K + (ch << 3);
    loa[c] = idx << 4;
  }
  size_t gb[BCH]; int lob[BCH];
#pragma unroll
  for (int c = 0; c < BCH; ++c) {
    int idx = tid + (c << 8);
    int row = idx >> 3;
    int ch = (idx & 7) ^ (row & 7);
    gb[c] = (size_t)(bn * BN + row) * K + (ch << 3);
    lob[c] = idx << 4;
  }

#define STAGE_G(t, bb) do { \
  _Pragma("unroll") for (int c = 0; c < ACH; ++c) \
    GLOAD16(A + ga[c] + (size_t)(t) * 64, (char*)As[bb] + loa[c]); \
  _Pragma("unroll") for (int c = 0; c < BCH; ++c) \
    GLOAD16(BT + gb[c] + (size_t)(t) * 64, (char*)Bs[bb] + lob[c]); \
} while (0)

  f32x4 acc[MF][4] = {};
  const int nt = K >> 6;

  STAGE_G(0, 0);
  STAGE_G(1, 1);

  for (int t = 0; t < nt; ++t) {
    if (t + 1 < nt) {
      asm volatile("s_waitcnt vmcnt(%0)" :: "i"(LOADS) : "memory");
    } else {
      asm volatile("s_waitcnt vmcnt(0)" ::: "memory");
    }
    __builtin_amdgcn_s_barrier();
    const u16* Ap = As[t & 1];
    const u16* Bp = Bs[t & 1];
    bf16x8 af[2][MF], bfr[2][4];
#pragma unroll
    for (int kk = 0; kk < 2; ++kk) {
#pragma unroll
      for (int m = 0; m < MF; ++m)
        af[kk][m] = *(const bf16x8*)(Ap + abase[m] + (((((kk << 2) | e4)) ^ ax[m]) << 3));
#pragma unroll
      for (int n = 0; n < 4; ++n)
        bfr[kk][n] = *(const bf16x8*)(Bp + bbase[n] + (((((kk << 2) | e4)) ^ bx[n]) << 3));
    }
    asm volatile("s_waitcnt lgkmcnt(0)" ::: "memory");
    __builtin_amdgcn_s_barrier();
    if (t + 2 < nt) STAGE_G(t + 2, t & 1);
    __builtin_amdgcn_s_setprio(1);
#pragma unroll
    for (int kk = 0; kk < 2; ++kk)
#pragma unroll
      for (int m = 0; m < MF; ++m)
#pragma unroll
        for (int n = 0; n < 4; ++n)
          acc[m][n] = __builtin_amdgcn_mfma_f32_16x16x32_bf16(af[kk][m], bfr[kk][n], acc[m][n], 0, 0, 0);
    __builtin_amdgcn_s_setprio(0);
  }
#undef STAGE_G

  const int rbase = bm * 128 + wm * (MF * 16);
  const int cbase = bn * BN + wn * 64;
#pragma unroll
  for (int m = 0; m < MF; ++m) {
#pragma unroll
    for (int n = 0; n < 4; ++n) {
      const int col = cbase + n * 16 + (lane & 15);
      const int row0 = rbase + m * 16 + ((lane >> 4) << 2);
      const float bv = bias[col];
#pragma unroll
      for (int r = 0; r < 4; ++r) {
        const int row = row0 + r;
        float v = acc[m][n][r] + bv;
        if (EPI == 1) {
          ((float*)outp)[(size_t)row * N + col] = v + res[(size_t)row * N + col];
        } else if (EPI == 2) {
          float tt = v * (1.0f + 0.044715f * v * v);
          float sg = 1.0f / (1.0f + __expf(-1.5957691216057308f * tt));
          ((u16*)outp)[(size_t)row * N + col] = f2bf(v * sg);
        } else {
          ((u16*)outp)[(size_t)row * N + col] = f2bf(v);
        }
      }
    }
  }
}

// ------- causal flash attention, 8-warp 32x32 swapped, NO-MAX softmax (C=8) -------
// softmax(s) = exp2(s'-8)/sum (exact; s' bounded << 120 so fp32 cannot overflow).
// -8 folded into QK accumulator init; l computed via ones-fragment MFMA.
__global__ __launch_bounds__(512, 2) void attn_kernel(const u16* __restrict__ QKV,
                                                      u16* __restrict__ O) {
  __shared__ __align__(16) u16 KV[4][4096];  // K0,K1,V0,V1; epilogue reuse
  const int T = 2048, LD = 3072;
  const int blk = blockIdx.x;
  const int xcd = blk & 7;
  const int i = blk >> 3;
  const int bh = xcd * 4 + (i & 3);
  const int p = i >> 2;
  const int b = bh >> 4, hd = bh & 15;
  const int tid = threadIdx.x;
  const int lane = tid & 63;
  const int w = tid >> 6;
  const int h = lane >> 5;
  const int cA = p, cB = 15 - p;
  const int myc = (w < 4) ? cA : cB;
  const int qwb = myc * 128 + (w & 3) * 32;
  const int qg = qwb + (lane & 31);
  const int diag = qwb >> 6;
  const int myNt = diag + 1;
  const int nt = 2 * cB + 2;

  const u16* Qb = QKV + (size_t)b * T * LD + hd * 64;
  const u16* Kb = Qb + 1024;
  const u16* Vb = Qb + 2048;

  const float QSC = 0.18033688011112042f;  // 0.125 * log2(e)
  bf16x8 qf[4];
#pragma unroll
  for (int s = 0; s < 4; ++s) {
    bf16x8 raw = *(const bf16x8*)(Qb + (size_t)qg * LD + s * 16 + h * 8);
    union { unsigned wd[4]; bf16x8 v; } u;
#pragma unroll
    for (int e = 0; e < 4; ++e)
      u.wd[e] = cvtpk(bf2f((u16)raw[2 * e]) * QSC, bf2f((u16)raw[2 * e + 1]) * QSC);
    qf[s] = u.v;
  }

  union PF { unsigned wd[4]; bf16x8 v; } ONES;
  ONES.wd[0] = 0x3F803F80u; ONES.wd[1] = 0x3F803F80u;
  ONES.wd[2] = 0x3F803F80u; ONES.wd[3] = 0x3F803F80u;

  f32x16 oacc[2] = {};
  f32x16 lacc = {};

  const int srow = tid >> 3;
  const int scol = tid & 7;
  const int kgc = ((scol ^ (srow & 7)) << 3);

  GLOAD16(Kb + (size_t)srow * LD + kgc, (char*)KV[0] + tid * 16);
  {
    bf16x8 vv0 = *(const bf16x8*)(Vb + (size_t)srow * LD + scol * 8);
#pragma unroll
    for (int e = 0; e < 8; ++e) {
      int d = scol * 8 + e;
      KV[2][(d << 6) | (srow & 7) | ((((srow >> 3) ^ e ^ scol) & 7) << 3)] = (u16)vv0[e];
    }
  }
  __syncthreads();

  int cur = 0;
  for (int j = 0; j < nt; ++j) {
    const bool pre = (j + 1 < nt);
    bf16x8 vv;
    if (pre) {
      GLOAD16(Kb + (size_t)((j + 1) * 64 + srow) * LD + kgc, (char*)KV[cur ^ 1] + tid * 16);
      vv = *(const bf16x8*)(Vb + (size_t)((j + 1) * 64 + srow) * LD + scol * 8);
    }

    if (j < myNt) {
      // S' - 8 = K*Q'^T + (-8)   (C-init carries the softmax shift)
      f32x16 sacc[2];
#pragma unroll
      for (int t = 0; t < 2; ++t)
#pragma unroll
        for (int r = 0; r < 16; ++r) sacc[t][r] = -8.0f;
      const u16* Kp = KV[cur];
      __builtin_amdgcn_s_setprio(1);
#pragma unroll
      for (int t = 0; t < 2; ++t) {
#pragma unroll
        for (int s = 0; s < 4; ++s) {
          int row = t * 32 + (lane & 31);
          bf16x8 kf = *(const bf16x8*)(Kp + (row << 6) + ((((2 * s + h) ^ (row & 7)) & 7) << 3));
          sacc[t] = __builtin_amdgcn_mfma_f32_32x32x16_bf16(kf, qf[s], sacc[t], 0, 0, 0);
        }
      }
      __builtin_amdgcn_s_setprio(0);

      if (j == diag) {
#pragma unroll
        for (int t = 0; t < 2; ++t)
#pragma unroll
          for (int r = 0; r < 16; ++r) {
            int key = (j << 6) + 32 * t + (r & 3) + 8 * (r >> 2) + 4 * h;
            if (key > qg) sacc[t][r] = -200.0f;   // exp2 -> 0
          }
      }

      // p = exp2(s'-8), directly; no max, no subtract, no rescale
#pragma unroll
      for (int t = 0; t < 2; ++t)
#pragma unroll
        for (int r = 0; r < 16; ++r)
          sacc[t][r] = exp2f(sacc[t][r]);

      // P^T B-fragments (cvt_pk + half swap)
      union PF pf[4];
#pragma unroll
      for (int t = 0; t < 2; ++t) {
#pragma unroll
        for (int kb = 0; kb < 2; ++kb) {
          int base = 8 * kb;
          unsigned A0 = cvtpk(sacc[t][base + 0], sacc[t][base + 1]);
          unsigned A2 = cvtpk(sacc[t][base + 2], sacc[t][base + 3]);
          unsigned A4 = cvtpk(sacc[t][base + 4], sacc[t][base + 5]);
          unsigned A6 = cvtpk(sacc[t][base + 6], sacc[t][base + 7]);
          unsigned S0 = (unsigned)__shfl_xor((int)(h ? A0 : A4), 32, 64);
          unsigned S2 = (unsigned)__shfl_xor((int)(h ? A2 : A6), 32, 64);
          PF& u = pf[2 * t + kb];
          u.wd[0] = h ? S0 : A0;
          u.wd[1] = h ? S2 : A2;
          u.wd[2] = h ? A4 : S0;
          u.wd[3] = h ? A6 : S2;
        }
      }

      // O^T += V^T * P^T ; l += ones * P^T (row-sum via matrix pipe)
      const u16* Vp = KV[2 + cur];
      __builtin_amdgcn_s_setprio(1);
#pragma unroll
      for (int ks = 0; ks < 4; ++ks) {
#pragma unroll
        for (int d2 = 0; d2 < 2; ++d2) {
          int d = d2 * 32 + (lane & 31);
          bf16x8 vf = *(const bf16x8*)(Vp + (d << 6) + ((((2 * ks + h) ^ (d & 7) ^ ((d >> 3) & 7)) & 7) << 3));
          oacc[d2] = __builtin_amdgcn_mfma_f32_32x32x16_bf16(vf, pf[ks].v, oacc[d2], 0, 0, 0);
        }
        lacc = __builtin_amdgcn_mfma_f32_32x32x16_bf16(ONES.v, pf[ks].v, lacc, 0, 0, 0);
      }
      __builtin_amdgcn_s_setprio(0);
    }

    if (pre) {
#pragma unroll
      for (int e = 0; e < 8; ++e) {
        int d = scol * 8 + e;
        KV[2 + (cur ^ 1)][(d << 6) | (srow & 7) | ((((srow >> 3) ^ e ^ scol) & 7) << 3)] = (u16)vv[e];
      }
    }
    __syncthreads();
    cur ^= 1;
  }

  // epilogue: l = lacc[0] (all rows equal); O = O^T / l, transpose via LDS, store
  const float rinv = 1.0f / lacc[0];
  u16* Ob = (u16*)KV;
  const int qloc = w * 32 + (lane & 31);
#pragma unroll
  for (int d2 = 0; d2 < 2; ++d2)
#pragma unroll
    for (int r = 0; r < 16; ++r) {
      int d = d2 * 32 + (r & 3) + 8 * (r >> 2) + 4 * h;
      Ob[(qloc << 6) | (d ^ ((qloc & 7) << 3))] = f2bf(oacc[d2][r] * rinv);
    }
  __syncthreads();
#pragma unroll
  for (int it = 0; it < 4; ++it) {
    int r = (tid >> 3) + it * 64;
    int c = tid & 7;
    bf16x8 val = *(const bf16x8*)(Ob + (r << 6) + (((c ^ (r & 7)) & 7) << 3));
    int qg2 = (r < 128) ? (cA * 128 + r) : (cB * 128 + (r - 128));
    *(bf16x8*)(O + (size_t)(b * T + qg2) * 1024 + hd * 64 + c * 8) = val;
  }
}

// ---------------- host launch ----------------
extern "C" void kernel_launch(void* const* d_in, const int* in_sizes, int n_in,
                              void* d_out, int out_size, void* d_ws, size_t ws_size,
                              hipStream_t stream) {
  const float* x      = (const float*)d_in[0];
  const float* gamma1 = (const float*)d_in[1];
  const float* beta1  = (const float*)d_in[2];
  const float* Wq     = (const float*)d_in[3];
  const float* bq     = (const float*)d_in[4];
  const float* Wk     = (const float*)d_in[5];
  const float* bk     = (const float*)d_in[6];
  const float* Wv     = (const float*)d_in[7];
  const float* bv     = (const float*)d_in[8];
  const float* Wo     = (const float*)d_in[9];
  const float* bo     = (const float*)d_in[10];
  const float* gamma2 = (const float*)d_in[11];
  const float* beta2  = (const float*)d_in[12];
  const float* W1     = (const float*)d_in[13];
  const float* b1     = (const float*)d_in[14];
  const float* W2     = (const float*)d_in[15];
  const float* b2     = (const float*)d_in[16];

  char* ws = (char*)d_ws;  // 64 MB layout
  u16* WqkvT = (u16*)(ws + 0 * MB);
  u16* WoT   = (u16*)(ws + 6 * MB);
  u16* W1T   = (u16*)(ws + 8 * MB);
  u16* W2T   = (u16*)(ws + 16 * MB);
  u16* qkv   = (u16*)(ws + 24 * MB);
  u16* hb    = (u16*)(ws + 24 * MB);
  u16* xn    = (u16*)(ws + 56 * MB);
  float* bqkv = (float*)d_out;
  float* x1 = (float*)d_out;

  const int M = 4096;

  wprep<<<dim3(16388), dim3(256), 0, stream>>>(Wq, Wk, Wv, Wo, W1, W2, bq, bk, bv,
                                               WqkvT, WoT, W1T, W2T, bqkv,
                                               x, gamma1, beta1, xn);

  gemm256sq<0><<<dim3(192), dim3(512), 0, stream>>>(xn, WqkvT, bqkv, qkv, M, 3072, 1024);

  attn_kernel<<<dim3(256), dim3(512), 0, stream>>>(qkv, xn);

  gemm_bt<1, 64><<<dim3(512), dim3(256), 0, stream>>>(xn, WoT, bo, x, x1, M, 1024, 1024);

  ln_kernel<<<dim3(M), dim3(256), 0, stream>>>(x1, gamma2, beta2, xn);

  gemm256sq<2><<<dim3(256), dim3(512), 0, stream>>>(xn, W1T, b1, hb, M, 4096, 1024);
  gemm_bt<1, 64><<<dim3(512), dim3(256), 0, stream>>>(hb, W2T, b2, x1, d_out, M, 1024, 4096);
}